// Round 15
// baseline (771.289 us; speedup 1.0000x reference)
//
#include <hip/hip_runtime.h>
#include <hip/hip_bf16.h>
#include <cstdint>

#define TEMPF 3.0f
#define EPSF 1e-5f

typedef __attribute__((ext_vector_type(8))) short bf16x8;
typedef __attribute__((ext_vector_type(4))) float f32x4;

// ---------- type helpers (f32 <-> bf16 staging) ----------
static __device__ __forceinline__ float bf2f(unsigned short u){
  union { unsigned u32; float f; } x; x.u32 = ((unsigned)u) << 16; return x.f;
}
static __device__ __forceinline__ unsigned short f2bf(float f){
  unsigned u = __float_as_uint(f);
  unsigned r = (u + 0x7fffu + ((u >> 16) & 1u)) >> 16;   // RNE
  return (unsigned short)r;
}
static __device__ __forceinline__ float4 ld4(const float* p){ return *(const float4*)p; }
static __device__ __forceinline__ float4 ld4(const __hip_bfloat16* p){
  ushort4 u = *(const ushort4*)p;
  return make_float4(bf2f(u.x), bf2f(u.y), bf2f(u.z), bf2f(u.w));
}
static __device__ __forceinline__ void st4(float* p, float4 v){ *(float4*)p = v; }
static __device__ __forceinline__ void st4(__hip_bfloat16* p, float4 v){
  *(ushort4*)p = make_ushort4(f2bf(v.x), f2bf(v.y), f2bf(v.z), f2bf(v.w));
}

// ---------- ordered-uint float encoding for atomic max ----------
static __device__ __forceinline__ unsigned fkey(float f){
  unsigned u = __float_as_uint(f);
  return (u & 0x80000000u) ? ~u : (u | 0x80000000u);
}
static __device__ __forceinline__ float fdec(unsigned k){
  return (k & 0x80000000u) ? __uint_as_float(k ^ 0x80000000u) : __uint_as_float(~k);
}

__device__ __forceinline__ float blockMax256(float v){
  __shared__ float red[4];
  #pragma unroll
  for(int off = 32; off; off >>= 1) v = fmaxf(v, __shfl_down(v, off));
  __syncthreads();
  if((threadIdx.x & 63) == 0) red[threadIdx.x >> 6] = v;
  __syncthreads();
  return fmaxf(fmaxf(red[0], red[1]), fmaxf(red[2], red[3]));
}
__device__ __forceinline__ float blockSum256(float v){
  __shared__ float red2[4];
  #pragma unroll
  for(int off = 32; off; off >>= 1) v += __shfl_down(v, off);
  __syncthreads();
  if((threadIdx.x & 63) == 0) red2[threadIdx.x >> 6] = v;
  __syncthreads();
  return red2[0] + red2[1] + red2[2] + red2[3];
}

// ---------- fused setup: zero y | detect mask dtype | wpack L1 | zero cb/zeros ----------
// grid 4137 x 256: b<4096 zero y; b==4096 detect; 4097..4120 wpack; 4121..4136 zero cb.
__global__ __launch_bounds__(256) void setup_k(
    const unsigned* __restrict__ mask, int* __restrict__ flag,
    unsigned* __restrict__ cb1, unsigned* __restrict__ cb2, unsigned* __restrict__ zeros,
    const float* __restrict__ wq1, const float* __restrict__ wsp1,
    const float* __restrict__ bq1, const float* __restrict__ bsp1,
    unsigned short* __restrict__ wp, float* __restrict__ bs,
    float4* __restrict__ y){
  const int b = blockIdx.x, tid = threadIdx.x;
  if(b < 4096){
    y[b * 256 + tid] = make_float4(0.f, 0.f, 0.f, 0.f);
  } else if(b == 4096){
    __shared__ int sa, sb;
    if(tid == 0){ sa = 0; sb = 0; }
    __syncthreads();
    int a = 0, b2 = 0;
    for(int i = tid; i < 1024; i += 256){
      unsigned w = mask[i];
      if(w != 0u && w != 1u) a = 1;
      if(w != 0u && w != 0x3f800000u) b2 = 1;
    }
    if(a)  atomicOr(&sa, 1);
    if(b2) atomicOr(&sb, 1);
    __syncthreads();
    if(tid == 0) *flag = (sa == 0) ? 0 : ((sb == 0) ? 1 : 2);  // 0=i32 1=f32 2=u8
  } else if(b < 4121){
    int i = (b - 4097) * 256 + tid;
    if(i < 6144){
      int path = i / 3072, rem = i % 3072, co = rem / 192, k = rem % 192;
      float v = 0.f;
      if(co < 10 && k < 180){
        const float* WA = path ? wsp1 : wq1;
        const float* WB = path ? wq1 : wsp1;
        int kk = k < 90 ? k : k - 90;
        int ci = kk / 9, t = kk % 9;
        v = (k < 90 ? WA : WB)[(co * 10 + ci) * 9 + t];
      }
      wp[i] = f2bf(v);
    }
    if(i < 32){
      int co = i & 15;
      bs[i] = co < 10 ? bq1[co] + bsp1[co] : 0.f;
    }
  } else {
    int i = (b - 4121) * 256 + tid;
    if(i < 4096){ cb1[i] = 0u; cb2[i] = 0u; }
    if(i < 1024) zeros[i] = 0u;
  }
}

// ---------- fused row max + col max (both read x once per role) ----------
// grid 4224: b<4096 rowmax(row=b); else colmax(blk=b-4096, 32 rows each).
__global__ __launch_bounds__(256) void rcmax_k(const float* __restrict__ x,
    float* __restrict__ rmax, unsigned* __restrict__ cbits){
  const int b = blockIdx.x, tid = threadIdx.x;
  if(b < 4096){
    float4 v = *(const float4*)(x + (size_t)b * 1024 + tid * 4);
    float m = fmaxf(fmaxf(v.x, v.y), fmaxf(v.z, v.w));
    m = blockMax256(m);
    if(tid == 0) rmax[b] = m;
  } else {
    int blk = b - 4096;
    int bb = blk >> 5, rg = blk & 31;
    const float* base = x + (size_t)bb * 1048576 + (size_t)rg * 32 * 1024;
    int col = tid * 4;
    float4 m = make_float4(-1e30f, -1e30f, -1e30f, -1e30f);
    for(int r = 0; r < 32; ++r){
      float4 v = *(const float4*)(base + r * 1024 + col);
      m.x = fmaxf(m.x, v.x); m.y = fmaxf(m.y, v.y);
      m.z = fmaxf(m.z, v.z); m.w = fmaxf(m.w, v.w);
    }
    unsigned* cb = cbits + (bb << 10) + col;
    atomicMax(cb + 0, fkey(m.x)); atomicMax(cb + 1, fkey(m.y));
    atomicMax(cb + 2, fkey(m.z)); atomicMax(cb + 3, fkey(m.w));
  }
}

// ---------- mutual matching elementwise ----------
__global__ __launch_bounds__(256) void mmapply_k(const float* __restrict__ x,
    const float* __restrict__ rmax, const unsigned* __restrict__ cbits,
    float* __restrict__ out){
  int idx4 = blockIdx.x * 256 + threadIdx.x;
  int b = idx4 >> 18;
  int rem = idx4 & 262143;
  int q = rem >> 8;
  int k = (rem & 255) * 4;
  float4 v = ((const float4*)x)[idx4];
  float ra = rmax[(b << 10) + q] + EPSF;
  const unsigned* cb = cbits + (b << 10) + k;
  float4 o;
  o.x = v.x * v.x * v.x / (ra * (fdec(cb[0]) + EPSF));
  o.y = v.y * v.y * v.y / (ra * (fdec(cb[1]) + EPSF));
  o.z = v.z * v.z * v.z / (ra * (fdec(cb[2]) + EPSF));
  o.w = v.w * v.w * v.w / (ra * (fdec(cb[3]) + EPSF));
  ((float4*)out)[idx4] = o;
}

// ---------- MFMA implicit-GEMM L1: r8 gather + prefetch + XCD swizzle, 512-thr blocks ----------
// block = 512 thr (8 waves) = one (path,hw) plane; wave handles 8 tiles of 16 s.
__global__ __launch_bounds__(512)
void convmm_k(const unsigned short* __restrict__ gin, unsigned short* __restrict__ gout,
              const unsigned short* __restrict__ wpack, const float* __restrict__ bias,
              unsigned inElem, unsigned outElem, unsigned zeroElem){
  __shared__ unsigned short sh[13600];          // [ci][34 rows][40 cols]
  const int tid = threadIdx.x;
  const int blk = ((blockIdx.x & 7) << 8) | (blockIdx.x >> 3);   // 2048 = 8 x 256
  const int path = blk >> 10;
  const int hw = blk & 1023;
  const int h = hw >> 5, w = hw & 31;
  const unsigned inB = inElem + (unsigned)path * 10485760u;
  const unsigned outB = outElem + (unsigned)path * 10485760u;

  for(int i = tid; i < 6800; i += 512) ((unsigned*)sh)[i] = 0u;
  __syncthreads();
  for(int idx = tid; idx < 2560; idx += 512){
    int ci = idx >> 8, s = (idx & 255) * 4;
    ushort4 v = *(const ushort4*)(gin + inB + ci * 1048576 + hw * 1024 + s);
    *(ushort4*)(sh + ci * 1360 + (1 + (s >> 5)) * 40 + 4 + (s & 31)) = v;
  }
  __syncthreads();

  const int l = tid & 63, wv = tid >> 6;       // wv 0..7
  const int g = l >> 4, n = l & 15;

  bf16x8 af[6];
  #pragma unroll
  for(int sl = 0; sl < 6; ++sl)
    af[sl] = *(const bf16x8*)(wpack + ((size_t)path * 16 + n) * 192 + sl * 32 + g * 8);
  f32x4 cb = *(const f32x4*)(bias + path * 16 + g * 4);

  unsigned b1i[24]; unsigned b2b[32]; unsigned msk2[4], msk5[4];
  unsigned s0 = (unsigned)wv * 128u;
  #pragma unroll
  for(int gg = 0; gg < 4; ++gg){
    if(g == gg){
      #pragma unroll
      for(int sl = 0; sl < 3; ++sl){
        #pragma unroll
        for(int j = 0; j < 8; ++j){
          const int k = sl * 32 + gg * 8 + j;
          unsigned v = zeroElem;
          if(k < 90){
            const int ci = k / 9, t = k % 9;
            const int hh = h + t / 3 - 1, ww = w + t % 3 - 1;
            if((unsigned)hh < 32u && (unsigned)ww < 32u)
              v = inB + (unsigned)ci * 1048576u + (unsigned)((hh * 32 + ww) * 1024) + (unsigned)n;
          }
          b1i[sl * 8 + j] = v + s0;
        }
      }
      #pragma unroll
      for(int sl = 2; sl < 6; ++sl){
        #pragma unroll
        for(int j = 0; j < 8; ++j){
          const int k = sl * 32 + gg * 8 + j;
          const int kp = (k >= 90 && k < 180) ? (k - 90) : 0;
          const int ci = kp / 9, t = kp % 9;
          b2b[(sl - 2) * 8 + j] = (unsigned)(ci * 1360 + (t / 3) * 40 + 3 + (t % 3) + n);
        }
      }
      #pragma unroll
      for(int p = 0; p < 4; ++p){
        const int ka = 64 + gg * 8 + 2 * p, kb = ka + 1;
        msk2[p] = ((ka >= 90) ? 0xFFFFu : 0u) | ((kb >= 90) ? 0xFFFF0000u : 0u);
        const int kc = 160 + gg * 8 + 2 * p, kd = kc + 1;
        msk5[p] = ((kc < 180) ? 0xFFFFu : 0u) | ((kd < 180) ? 0xFFFF0000u : 0u);
      }
    }
  }

  // prologue: prefetch iteration 0's gathers
  unsigned short ga[24], gb[24];
  #pragma unroll
  for(int m = 0; m < 24; ++m) ga[m] = gin[b1i[m]];
  #pragma unroll
  for(int m = 0; m < 24; ++m) b1i[m] += 16u;

#define CMM_STEP(CUR, NXT)                                                        \
  {                                                                               \
    _Pragma("unroll")                                                             \
    for(int m = 0; m < 24; ++m) NXT[m] = gin[b1i[m]];                             \
    _Pragma("unroll")                                                             \
    for(int m = 0; m < 24; ++m) b1i[m] += 16u;                                    \
    const unsigned rowcs = ((s0 >> 5) * 40u) + (s0 & 16u);                        \
    union { unsigned u[4]; bf16x8 v; } B0, B1, B2, B3, B4, B5;                    \
    _Pragma("unroll")                                                             \
    for(int p = 0; p < 4; ++p){                                                   \
      B0.u[p] = (unsigned)CUR[2*p]    | ((unsigned)CUR[2*p+1] << 16);             \
      B1.u[p] = (unsigned)CUR[8+2*p]  | ((unsigned)CUR[8+2*p+1] << 16);           \
      unsigned glo = (unsigned)CUR[16+2*p] | ((unsigned)CUR[16+2*p+1] << 16);     \
      unsigned llo = (unsigned)sh[b2b[2*p] + rowcs] |                             \
                     ((unsigned)sh[b2b[2*p+1] + rowcs] << 16);                    \
      B2.u[p] = glo | (llo & msk2[p]);                                            \
      B3.u[p] = (unsigned)sh[b2b[8+2*p]  + rowcs] |                               \
                ((unsigned)sh[b2b[8+2*p+1]  + rowcs] << 16);                      \
      B4.u[p] = (unsigned)sh[b2b[16+2*p] + rowcs] |                               \
                ((unsigned)sh[b2b[16+2*p+1] + rowcs] << 16);                      \
      B5.u[p] = ((unsigned)sh[b2b[24+2*p] + rowcs] |                              \
                 ((unsigned)sh[b2b[24+2*p+1] + rowcs] << 16)) & msk5[p];          \
    }                                                                             \
    __builtin_amdgcn_s_setprio(1);                                                \
    f32x4 acc = __builtin_amdgcn_mfma_f32_16x16x32_bf16(af[0], B0.v, cb, 0, 0, 0);\
    acc = __builtin_amdgcn_mfma_f32_16x16x32_bf16(af[1], B1.v, acc, 0, 0, 0);     \
    acc = __builtin_amdgcn_mfma_f32_16x16x32_bf16(af[2], B2.v, acc, 0, 0, 0);     \
    acc = __builtin_amdgcn_mfma_f32_16x16x32_bf16(af[3], B3.v, acc, 0, 0, 0);     \
    acc = __builtin_amdgcn_mfma_f32_16x16x32_bf16(af[4], B4.v, acc, 0, 0, 0);     \
    acc = __builtin_amdgcn_mfma_f32_16x16x32_bf16(af[5], B5.v, acc, 0, 0, 0);     \
    __builtin_amdgcn_s_setprio(0);                                                \
    _Pragma("unroll")                                                             \
    for(int r = 0; r < 4; ++r){                                                   \
      const int co = g * 4 + r;                                                   \
      if(co < 10)                                                                 \
        gout[outB + (unsigned)co * 1048576u + (unsigned)(hw * 1024) + s0 + n] =   \
            f2bf(fmaxf(acc[r], 0.f));                                             \
    }                                                                             \
    s0 += 16u;                                                                    \
  }

  for(int itp = 0; itp < 4; ++itp){
    CMM_STEP(ga, gb)
    CMM_STEP(gb, ga)
  }
#undef CMM_STEP
}

// ---------- fused dual-path conv layer L0 (VALU, r5-proven) + XCD swizzle ----------
template<int CI, typename TI, typename TO>
__global__ __launch_bounds__(128, 4) void conv12_k(
    const TI* __restrict__ in, TO* __restrict__ out,
    const float* __restrict__ wq, const float* __restrict__ wsp,
    const float* __restrict__ bq, const float* __restrict__ bsp,
    size_t in_pstride){
  __shared__ float P[18][36];
  const int tid = threadIdx.x;
  const int blk = ((blockIdx.x & 7) << 9) | (blockIdx.x >> 3);   // 4096 = 8 x 512
  const int path = blk >> 11;
  const int r0 = blk & 2047;
  const int strip = r0 & 1;
  const int hw = r0 >> 1;
  const int w = hw & 31, h = hw >> 5;
  const int lr = tid >> 3;
  const int c  = (tid & 7) * 4;
  const int own = hw * 1024 + strip * 512 + tid * 4;
  const int halo_src = hw * 1024 + (strip ? 15 * 32 : 16 * 32) + (tid & 7) * 4;
  const int hrow = strip ? 0 : 17;
  const float* wA = path ? wsp : wq;
  const float* wB = path ? wq : wsp;
  const TI* inp = in + (size_t)path * in_pstride;
  TO* outp = out + (size_t)path * 10485760;

  bool valid[9];
  #pragma unroll
  for(int dh = 0; dh < 3; ++dh)
    #pragma unroll
    for(int dw = 0; dw < 3; ++dw)
      valid[dh * 3 + dw] = ((unsigned)(h + dh - 1) < 32u) && ((unsigned)(w + dw - 1) < 32u);

  for(int i = tid; i < 18 * 36; i += 128) ((float*)P)[i] = 0.f;

  float acc[10][4];
  #pragma unroll
  for(int co = 0; co < 10; ++co){
    float bv = bq[co] + bsp[co];
    acc[co][0] = bv; acc[co][1] = bv; acc[co][2] = bv; acc[co][3] = bv;
  }

  for(int ci = 0; ci < CI; ++ci){
    const TI* base = inp + (size_t)ci * 1048576;
    float4 qv[9];
    #pragma unroll
    for(int dh = 0; dh < 3; ++dh){
      #pragma unroll
      for(int dw = 0; dw < 3; ++dw){
        const int t = dh * 3 + dw;
        float4 vv = make_float4(0.f, 0.f, 0.f, 0.f);
        if(valid[t]) vv = ld4(base + own + ((dh - 1) * 32 + (dw - 1)) * 1024);
        qv[t] = vv;
      }
    }
    float4 hv = make_float4(0.f, 0.f, 0.f, 0.f);
    if(tid < 8) hv = ld4(base + halo_src);

    __syncthreads();
    *(float4*)&P[1 + lr][c] = qv[4];
    if(tid < 8) *(float4*)&P[hrow][tid * 4] = hv;
    __syncthreads();

    float pr[3][6];
    #pragma unroll
    for(int k1 = 0; k1 < 3; ++k1){
      const float* row = &P[lr + k1][0];
      float4 mid = *(const float4*)(row + c);
      pr[k1][0] = row[c == 0 ? 32 : c - 1];
      pr[k1][1] = mid.x; pr[k1][2] = mid.y; pr[k1][3] = mid.z; pr[k1][4] = mid.w;
      pr[k1][5] = row[c + 4];
    }

    #pragma unroll
    for(int co = 0; co < 10; ++co){
      const float* wa = wA + (co * CI + ci) * 9;
      const float* wb = wB + (co * CI + ci) * 9;
      #pragma unroll
      for(int t = 0; t < 9; ++t){
        float wv = wa[t];
        acc[co][0] += wv * qv[t].x; acc[co][1] += wv * qv[t].y;
        acc[co][2] += wv * qv[t].z; acc[co][3] += wv * qv[t].w;
      }
      #pragma unroll
      for(int k1 = 0; k1 < 3; ++k1){
        #pragma unroll
        for(int k2 = 0; k2 < 3; ++k2){
          float wv = wb[k1 * 3 + k2];
          #pragma unroll
          for(int j = 0; j < 4; ++j) acc[co][j] += wv * pr[k1][k2 + j];
        }
      }
    }
  }

  #pragma unroll
  for(int co = 0; co < 10; ++co){
    float4 r;
    r.x = fmaxf(acc[co][0], 0.f); r.y = fmaxf(acc[co][1], 0.f);
    r.z = fmaxf(acc[co][2], 0.f); r.w = fmaxf(acc[co][3], 0.f);
    st4(outp + (size_t)co * 1048576 + own, r);
  }
}

// ---------- path-split last layer (CO=1): atomicAdd relu into zeroed y + XCD swizzle ----------
__global__ __launch_bounds__(128, 4) void conv3_k(
    const __hip_bfloat16* __restrict__ in,      // t2 base: [path][10][1M]
    const float* __restrict__ wq, const float* __restrict__ wsp,
    const float* __restrict__ bq, const float* __restrict__ bsp,
    float* __restrict__ yb){
  __shared__ float P[18][36];
  const int tid = threadIdx.x;
  const int blk = ((blockIdx.x & 7) << 9) | (blockIdx.x >> 3);   // 4096 = 8 x 512
  const int path = blk >> 11;
  const int r0 = blk & 2047;
  const int strip = r0 & 1;
  const int hw = r0 >> 1;
  const int w = hw & 31, h = hw >> 5;
  const int lr = tid >> 3;
  const int c  = (tid & 7) * 4;
  const int own = hw * 1024 + strip * 512 + tid * 4;
  const int halo_src = hw * 1024 + (strip ? 15 * 32 : 16 * 32) + (tid & 7) * 4;
  const int hrow = strip ? 0 : 17;
  const float* wA = path ? wsp : wq;
  const float* wB = path ? wq : wsp;
  const __hip_bfloat16* inp = in + (size_t)path * 10485760;

  bool valid[9];
  #pragma unroll
  for(int dh = 0; dh < 3; ++dh)
    #pragma unroll
    for(int dw = 0; dw < 3; ++dw)
      valid[dh * 3 + dw] = ((unsigned)(h + dh - 1) < 32u) && ((unsigned)(w + dw - 1) < 32u);

  for(int i = tid; i < 18 * 36; i += 128) ((float*)P)[i] = 0.f;

  float bv = bq[0] + bsp[0];
  float a0 = bv, a1 = bv, a2 = bv, a3 = bv;

  for(int ci = 0; ci < 10; ++ci){
    const __hip_bfloat16* base = inp + (size_t)ci * 1048576;
    float4 qv[9];
    #pragma unroll
    for(int dh = 0; dh < 3; ++dh){
      #pragma unroll
      for(int dw = 0; dw < 3; ++dw){
        const int t = dh * 3 + dw;
        float4 vv = make_float4(0.f, 0.f, 0.f, 0.f);
        if(valid[t]) vv = ld4(base + own + ((dh - 1) * 32 + (dw - 1)) * 1024);
        qv[t] = vv;
      }
    }
    float4 hv = make_float4(0.f, 0.f, 0.f, 0.f);
    if(tid < 8) hv = ld4(base + halo_src);

    __syncthreads();
    *(float4*)&P[1 + lr][c] = qv[4];
    if(tid < 8) *(float4*)&P[hrow][tid * 4] = hv;
    __syncthreads();

    float pr[3][6];
    #pragma unroll
    for(int k1 = 0; k1 < 3; ++k1){
      const float* row = &P[lr + k1][0];
      float4 mid = *(const float4*)(row + c);
      pr[k1][0] = row[c == 0 ? 32 : c - 1];
      pr[k1][1] = mid.x; pr[k1][2] = mid.y; pr[k1][3] = mid.z; pr[k1][4] = mid.w;
      pr[k1][5] = row[c + 4];
    }

    const float* wa = wA + ci * 9;
    const float* wb = wB + ci * 9;
    #pragma unroll
    for(int t = 0; t < 9; ++t){
      float wv = wa[t];
      a0 += wv * qv[t].x; a1 += wv * qv[t].y;
      a2 += wv * qv[t].z; a3 += wv * qv[t].w;
    }
    #pragma unroll
    for(int k1 = 0; k1 < 3; ++k1){
      #pragma unroll
      for(int k2 = 0; k2 < 3; ++k2){
        float wv = wb[k1 * 3 + k2];
        a0 += wv * pr[k1][k2 + 0];
        a1 += wv * pr[k1][k2 + 1];
        a2 += wv * pr[k1][k2 + 2];
        a3 += wv * pr[k1][k2 + 3];
      }
    }
  }

  atomicAdd(yb + own + 0, fmaxf(a0, 0.f));
  atomicAdd(yb + own + 1, fmaxf(a1, 0.f));
  atomicAdd(yb + own + 2, fmaxf(a2, 0.f));
  atomicAdd(yb + own + 3, fmaxf(a3, 0.f));
}

// ---------- mm2 + mask + softmax fused, one block per (b,q) row ----------
__global__ __launch_bounds__(256) void softmax_k(
    const float* __restrict__ y, const float* __restrict__ rmax,
    const unsigned* __restrict__ cbits, const void* __restrict__ mask,
    const int* __restrict__ mode, float* __restrict__ attn){
  int row = blockIdx.x;          // b*1024+q
  int b = row >> 10;
  int tid = threadIdx.x;
  int kc = tid * 4;
  float ra = rmax[row] + EPSF;
  float4 v = *(const float4*)(y + (size_t)row * 1024 + kc);
  int md = *mode;
  float vv[4] = {v.x, v.y, v.z, v.w};
  float s[4];
  #pragma unroll
  for(int j = 0; j < 4; ++j){
    int k = kc + j;
    float cb = fdec(cbits[(b << 10) + k]) + EPSF;
    float m = vv[j] * vv[j] * vv[j] / (ra * cb);
    bool msk;
    if(md == 0)      msk = ((const int*)mask)[(b << 10) + k] != 0;
    else if(md == 1) msk = ((const float*)mask)[(b << 10) + k] != 0.f;
    else             msk = ((const unsigned char*)mask)[(b << 10) + k] != 0;
    if(msk) m = 1e-4f;
    s[j] = m * TEMPF;
  }
  float mx = fmaxf(fmaxf(s[0], s[1]), fmaxf(s[2], s[3]));
  mx = blockMax256(mx);
  float e[4]; float sum = 0.f;
  #pragma unroll
  for(int j = 0; j < 4; ++j){ e[j] = expf(s[j] - mx); sum += e[j]; }
  sum = blockSum256(sum);
  float inv = 1.0f / sum;
  float4 o; o.x = e[0] * inv; o.y = e[1] * inv; o.z = e[2] * inv; o.w = e[3] * inv;
  *(float4*)(attn + (size_t)row * 1024 + kc) = o;
}

// ---------- partial[ks][b,c,q] = sum_{k in split ks} v[b,c,k]*attn[b,q,k] ----------
__global__ __launch_bounds__(256) void bmm_k(const float* __restrict__ v,
    const float* __restrict__ attn, float* __restrict__ part){
  __shared__ float At[64][68];
  __shared__ float Bt[64][68];
  int b  = blockIdx.y >> 2;
  int ks = blockIdx.y & 3;
  int ct = blockIdx.x >> 4, qt = blockIdx.x & 15;
  int tid = threadIdx.x;
  int c0 = ct * 64, q0 = qt * 64;
  int tx = tid & 15, ty = tid >> 4;
  float acc[4][4] = {};
  for(int k0 = ks * 256; k0 < ks * 256 + 256; k0 += 64){
    #pragma unroll
    for(int l = 0; l < 4; ++l){
      int r = (tid >> 4) + l * 16;
      int cc = (tid & 15) * 4;
      *(float4*)&At[r][cc] = *(const float4*)(v    + ((size_t)b * 256  + c0 + r) * 1024 + k0 + cc);
      *(float4*)&Bt[r][cc] = *(const float4*)(attn + ((size_t)b * 1024 + q0 + r) * 1024 + k0 + cc);
    }
    __syncthreads();
    #pragma unroll 4
    for(int kk = 0; kk < 64; ++kk){
      float a_[4], b_[4];
      #pragma unroll
      for(int i = 0; i < 4; ++i){ a_[i] = At[ty * 4 + i][kk]; b_[i] = Bt[tx * 4 + i][kk]; }
      #pragma unroll
      for(int i = 0; i < 4; ++i)
        #pragma unroll
        for(int j = 0; j < 4; ++j) acc[i][j] += a_[i] * b_[j];
    }
    __syncthreads();
  }
  float* pb = part + (size_t)ks * 1048576;
  #pragma unroll
  for(int i = 0; i < 4; ++i){
    float4 r; r.x = acc[i][0]; r.y = acc[i][1]; r.z = acc[i][2]; r.w = acc[i][3];
    *(float4*)(pb + ((size_t)b * 256 + c0 + ty * 4 + i) * 1024 + q0 + tx * 4) = r;
  }
}

__global__ __launch_bounds__(256) void bmmred_k(const float* __restrict__ part,
                                                float* __restrict__ out){
  int i = blockIdx.x * 256 + threadIdx.x;      // over 262144 float4
  const float4* p = (const float4*)part;
  float4 a = p[i], b = p[i + 262144], cc = p[i + 524288], d = p[i + 786432];
  float4 o;
  o.x = a.x + b.x + cc.x + d.x;
  o.y = a.y + b.y + cc.y + d.y;
  o.z = a.z + b.z + cc.z + d.z;
  o.w = a.w + b.w + cc.w + d.w;
  ((float4*)out)[i] = o;
}

extern "C" void kernel_launch(void* const* d_in, const int* in_sizes, int n_in,
                              void* d_out, int out_size, void* d_ws, size_t ws_size,
                              hipStream_t stream){
  (void)in_sizes; (void)n_in; (void)out_size; (void)ws_size;
  const float* corr = (const float*)d_in[0];
  const float* v    = (const float*)d_in[1];
  const void*  mask = d_in[2];
  const float* wq[3]  = {(const float*)d_in[3],  (const float*)d_in[7],  (const float*)d_in[11]};
  const float* bq[3]  = {(const float*)d_in[4],  (const float*)d_in[8],  (const float*)d_in[12]};
  const float* wsp[3] = {(const float*)d_in[5],  (const float*)d_in[9],  (const float*)d_in[13]};
  const float* bsp[3] = {(const float*)d_in[6],  (const float*)d_in[10], (const float*)d_in[14]};
  float* out = (float*)d_out;

  // ---- workspace layout: total exactly 117,571,584 B (proven fit) ----
  char* ws = (char*)d_ws;
  float* x0 = (float*)(ws);                      // 16.78 MB f32
  float* y  = (float*)(ws + 16777216);           // 16.78 MB f32
  char* aux = ws + 33554432;                     // 128 KiB
  float*    rmax1 = (float*)(aux);
  unsigned* cb1   = (unsigned*)(aux + 16384);
  float*    rmax2 = (float*)(aux + 32768);
  unsigned* cb2   = (unsigned*)(aux + 49152);
  int*      flag  = (int*)(aux + 65536);
  unsigned short* wp = (unsigned short*)(aux + 69632);  // 12,288 B
  float*          bs = (float*)(aux + 81920);          // 128 B
  unsigned* zeros = (unsigned*)(aux + 98304);          // 4,096 B zero stripe
  char* treg = ws + 33685504;                    // 2 x 41,943,040 B bf16 dual-path buffers
  __hip_bfloat16* t1 = (__hip_bfloat16*)(treg);                 // [path][10][1M]
  __hip_bfloat16* t2 = (__hip_bfloat16*)(treg + 41943040);
  float* attn = x0;
  float* part = (float*)treg;

  // u16-element offsets within ws (for convmm 32-bit addressing)
  const unsigned t1Elem   = 33685504u / 2u;
  const unsigned t2Elem   = 75628544u / 2u;
  const unsigned zeroElem = 33652736u / 2u;

  setup_k<<<4137, 256, 0, stream>>>((const unsigned*)mask, flag, cb1, cb2, zeros,
                                    wq[1], wsp[1], bq[1], bsp[1], wp, bs, (float4*)y);
  rcmax_k<<<4224, 256, 0, stream>>>(corr, rmax1, cb1);
  mmapply_k<<<4096, 256, 0, stream>>>(corr, rmax1, cb1, x0);

  for(int bb = 0; bb < 4; ++bb){
    const float* xb = x0 + (size_t)bb * 1048576;
    float*       yb = y  + (size_t)bb * 1048576;
    conv12_k<1, float, __hip_bfloat16><<<4096, 128, 0, stream>>>(
        xb, t1, wq[0], wsp[0], bq[0], bsp[0], 0);
    convmm_k<<<2048, 512, 0, stream>>>(
        (const unsigned short*)ws, (unsigned short*)ws, wp, bs, t1Elem, t2Elem, zeroElem);
    conv3_k<<<4096, 128, 0, stream>>>(
        t2, wq[2], wsp[2], bq[2], bsp[2], yb);
  }

  rcmax_k<<<4224, 256, 0, stream>>>(y, rmax2, cb2);
  softmax_k<<<4096, 256, 0, stream>>>(y, rmax2, cb2, mask, flag, attn);
  bmm_k<<<dim3(64, 16), 256, 0, stream>>>(v, attn, part);
  bmmred_k<<<1024, 256, 0, stream>>>(part, out);
}

// Round 16
// 697.587 us; speedup vs baseline: 1.1057x; 1.1057x over previous
//
#include <hip/hip_runtime.h>
#include <hip/hip_bf16.h>
#include <cstdint>

#define TEMPF 3.0f
#define EPSF 1e-5f

typedef __attribute__((ext_vector_type(8))) short bf16x8;
typedef __attribute__((ext_vector_type(4))) float f32x4;

// ---------- type helpers (f32 <-> bf16 staging) ----------
static __device__ __forceinline__ float bf2f(unsigned short u){
  union { unsigned u32; float f; } x; x.u32 = ((unsigned)u) << 16; return x.f;
}
static __device__ __forceinline__ unsigned short f2bf(float f){
  unsigned u = __float_as_uint(f);
  unsigned r = (u + 0x7fffu + ((u >> 16) & 1u)) >> 16;   // RNE
  return (unsigned short)r;
}
static __device__ __forceinline__ float4 ld4(const float* p){ return *(const float4*)p; }
static __device__ __forceinline__ float4 ld4(const __hip_bfloat16* p){
  ushort4 u = *(const ushort4*)p;
  return make_float4(bf2f(u.x), bf2f(u.y), bf2f(u.z), bf2f(u.w));
}
static __device__ __forceinline__ void st4(float* p, float4 v){ *(float4*)p = v; }
static __device__ __forceinline__ void st4(__hip_bfloat16* p, float4 v){
  *(ushort4*)p = make_ushort4(f2bf(v.x), f2bf(v.y), f2bf(v.z), f2bf(v.w));
}

// ---------- ordered-uint float encoding for atomic max ----------
static __device__ __forceinline__ unsigned fkey(float f){
  unsigned u = __float_as_uint(f);
  return (u & 0x80000000u) ? ~u : (u | 0x80000000u);
}
static __device__ __forceinline__ float fdec(unsigned k){
  return (k & 0x80000000u) ? __uint_as_float(k ^ 0x80000000u) : __uint_as_float(~k);
}

__device__ __forceinline__ float blockMax256(float v){
  __shared__ float red[4];
  #pragma unroll
  for(int off = 32; off; off >>= 1) v = fmaxf(v, __shfl_down(v, off));
  __syncthreads();
  if((threadIdx.x & 63) == 0) red[threadIdx.x >> 6] = v;
  __syncthreads();
  return fmaxf(fmaxf(red[0], red[1]), fmaxf(red[2], red[3]));
}
__device__ __forceinline__ float blockSum256(float v){
  __shared__ float red2[4];
  #pragma unroll
  for(int off = 32; off; off >>= 1) v += __shfl_down(v, off);
  __syncthreads();
  if((threadIdx.x & 63) == 0) red2[threadIdx.x >> 6] = v;
  __syncthreads();
  return red2[0] + red2[1] + red2[2] + red2[3];
}

// ---------- fused setup: zero y | detect mask dtype | wpack L1 | zero cb/zeros ----------
__global__ __launch_bounds__(256) void setup_k(
    const unsigned* __restrict__ mask, int* __restrict__ flag,
    unsigned* __restrict__ cb1, unsigned* __restrict__ cb2, unsigned* __restrict__ zeros,
    const float* __restrict__ wq1, const float* __restrict__ wsp1,
    const float* __restrict__ bq1, const float* __restrict__ bsp1,
    unsigned short* __restrict__ wp, float* __restrict__ bs,
    float4* __restrict__ y){
  const int b = blockIdx.x, tid = threadIdx.x;
  if(b < 4096){
    y[b * 256 + tid] = make_float4(0.f, 0.f, 0.f, 0.f);
  } else if(b == 4096){
    __shared__ int sa, sb;
    if(tid == 0){ sa = 0; sb = 0; }
    __syncthreads();
    int a = 0, b2 = 0;
    for(int i = tid; i < 1024; i += 256){
      unsigned w = mask[i];
      if(w != 0u && w != 1u) a = 1;
      if(w != 0u && w != 0x3f800000u) b2 = 1;
    }
    if(a)  atomicOr(&sa, 1);
    if(b2) atomicOr(&sb, 1);
    __syncthreads();
    if(tid == 0) *flag = (sa == 0) ? 0 : ((sb == 0) ? 1 : 2);  // 0=i32 1=f32 2=u8
  } else if(b < 4121){
    int i = (b - 4097) * 256 + tid;
    if(i < 6144){
      int path = i / 3072, rem = i % 3072, co = rem / 192, k = rem % 192;
      float v = 0.f;
      if(co < 10 && k < 180){
        const float* WA = path ? wsp1 : wq1;
        const float* WB = path ? wq1 : wsp1;
        int kk = k < 90 ? k : k - 90;
        int ci = kk / 9, t = kk % 9;
        v = (k < 90 ? WA : WB)[(co * 10 + ci) * 9 + t];
      }
      wp[i] = f2bf(v);
    }
    if(i < 32){
      int co = i & 15;
      bs[i] = co < 10 ? bq1[co] + bsp1[co] : 0.f;
    }
  } else {
    int i = (b - 4121) * 256 + tid;
    if(i < 4096){ cb1[i] = 0u; cb2[i] = 0u; }
    if(i < 1024) zeros[i] = 0u;
  }
}

// ---------- fused row max + col max ----------
__global__ __launch_bounds__(256) void rcmax_k(const float* __restrict__ x,
    float* __restrict__ rmax, unsigned* __restrict__ cbits){
  const int b = blockIdx.x, tid = threadIdx.x;
  if(b < 4096){
    float4 v = *(const float4*)(x + (size_t)b * 1024 + tid * 4);
    float m = fmaxf(fmaxf(v.x, v.y), fmaxf(v.z, v.w));
    m = blockMax256(m);
    if(tid == 0) rmax[b] = m;
  } else {
    int blk = b - 4096;
    int bb = blk >> 5, rg = blk & 31;
    const float* base = x + (size_t)bb * 1048576 + (size_t)rg * 32 * 1024;
    int col = tid * 4;
    float4 m = make_float4(-1e30f, -1e30f, -1e30f, -1e30f);
    for(int r = 0; r < 32; ++r){
      float4 v = *(const float4*)(base + r * 1024 + col);
      m.x = fmaxf(m.x, v.x); m.y = fmaxf(m.y, v.y);
      m.z = fmaxf(m.z, v.z); m.w = fmaxf(m.w, v.w);
    }
    unsigned* cb = cbits + (bb << 10) + col;
    atomicMax(cb + 0, fkey(m.x)); atomicMax(cb + 1, fkey(m.y));
    atomicMax(cb + 2, fkey(m.z)); atomicMax(cb + 3, fkey(m.w));
  }
}

// ---------- mutual matching elementwise ----------
__global__ __launch_bounds__(256) void mmapply_k(const float* __restrict__ x,
    const float* __restrict__ rmax, const unsigned* __restrict__ cbits,
    float* __restrict__ out){
  int idx4 = blockIdx.x * 256 + threadIdx.x;
  int b = idx4 >> 18;
  int rem = idx4 & 262143;
  int q = rem >> 8;
  int k = (rem & 255) * 4;
  float4 v = ((const float4*)x)[idx4];
  float ra = rmax[(b << 10) + q] + EPSF;
  const unsigned* cb = cbits + (b << 10) + k;
  float4 o;
  o.x = v.x * v.x * v.x / (ra * (fdec(cb[0]) + EPSF));
  o.y = v.y * v.y * v.y / (ra * (fdec(cb[1]) + EPSF));
  o.z = v.z * v.z * v.z / (ra * (fdec(cb[2]) + EPSF));
  o.w = v.w * v.w * v.w / (ra * (fdec(cb[3]) + EPSF));
  ((float4*)out)[idx4] = o;
}

// ---------- MFMA implicit-GEMM L1: r8 gather + prefetch + XCD swizzle (r14-proven, 91us) ----------
__global__ __launch_bounds__(256)
void convmm_k(const unsigned short* __restrict__ gin, unsigned short* __restrict__ gout,
              const unsigned short* __restrict__ wpack, const float* __restrict__ bias,
              unsigned inElem, unsigned outElem, unsigned zeroElem){
  __shared__ unsigned short sh[13600];          // [ci][34 rows][40 cols]
  const int tid = threadIdx.x;
  const int blk = ((blockIdx.x & 7) << 8) | (blockIdx.x >> 3);   // 2048 = 8 x 256
  const int path = blk >> 10;
  const int hw = blk & 1023;
  const int h = hw >> 5, w = hw & 31;
  const unsigned inB = inElem + (unsigned)path * 10485760u;
  const unsigned outB = outElem + (unsigned)path * 10485760u;

  for(int i = tid; i < 6800; i += 256) ((unsigned*)sh)[i] = 0u;
  __syncthreads();
  for(int idx = tid; idx < 2560; idx += 256){
    int ci = idx >> 8, s = (idx & 255) * 4;
    ushort4 v = *(const ushort4*)(gin + inB + ci * 1048576 + hw * 1024 + s);
    *(ushort4*)(sh + ci * 1360 + (1 + (s >> 5)) * 40 + 4 + (s & 31)) = v;
  }
  __syncthreads();

  const int l = tid & 63, wv = tid >> 6;
  const int g = l >> 4, n = l & 15;

  bf16x8 af[6];
  #pragma unroll
  for(int sl = 0; sl < 6; ++sl)
    af[sl] = *(const bf16x8*)(wpack + ((size_t)path * 16 + n) * 192 + sl * 32 + g * 8);
  f32x4 cb = *(const f32x4*)(bias + path * 16 + g * 4);

  unsigned b1i[24]; unsigned b2b[32]; unsigned msk2[4], msk5[4];
  unsigned s0 = (unsigned)wv * 256u;
  #pragma unroll
  for(int gg = 0; gg < 4; ++gg){
    if(g == gg){
      #pragma unroll
      for(int sl = 0; sl < 3; ++sl){
        #pragma unroll
        for(int j = 0; j < 8; ++j){
          const int k = sl * 32 + gg * 8 + j;
          unsigned v = zeroElem;
          if(k < 90){
            const int ci = k / 9, t = k % 9;
            const int hh = h + t / 3 - 1, ww = w + t % 3 - 1;
            if((unsigned)hh < 32u && (unsigned)ww < 32u)
              v = inB + (unsigned)ci * 1048576u + (unsigned)((hh * 32 + ww) * 1024) + (unsigned)n;
          }
          b1i[sl * 8 + j] = v + s0;
        }
      }
      #pragma unroll
      for(int sl = 2; sl < 6; ++sl){
        #pragma unroll
        for(int j = 0; j < 8; ++j){
          const int k = sl * 32 + gg * 8 + j;
          const int kp = (k >= 90 && k < 180) ? (k - 90) : 0;
          const int ci = kp / 9, t = kp % 9;
          b2b[(sl - 2) * 8 + j] = (unsigned)(ci * 1360 + (t / 3) * 40 + 3 + (t % 3) + n);
        }
      }
      #pragma unroll
      for(int p = 0; p < 4; ++p){
        const int ka = 64 + gg * 8 + 2 * p, kb = ka + 1;
        msk2[p] = ((ka >= 90) ? 0xFFFFu : 0u) | ((kb >= 90) ? 0xFFFF0000u : 0u);
        const int kc = 160 + gg * 8 + 2 * p, kd = kc + 1;
        msk5[p] = ((kc < 180) ? 0xFFFFu : 0u) | ((kd < 180) ? 0xFFFF0000u : 0u);
      }
    }
  }

  // prologue: prefetch iteration 0's gathers
  unsigned short ga[24], gb[24];
  #pragma unroll
  for(int m = 0; m < 24; ++m) ga[m] = gin[b1i[m]];
  #pragma unroll
  for(int m = 0; m < 24; ++m) b1i[m] += 16u;

#define CMM_STEP(CUR, NXT)                                                        \
  {                                                                               \
    _Pragma("unroll")                                                             \
    for(int m = 0; m < 24; ++m) NXT[m] = gin[b1i[m]];                             \
    _Pragma("unroll")                                                             \
    for(int m = 0; m < 24; ++m) b1i[m] += 16u;                                    \
    const unsigned rowcs = ((s0 >> 5) * 40u) + (s0 & 16u);                        \
    union { unsigned u[4]; bf16x8 v; } B0, B1, B2, B3, B4, B5;                    \
    _Pragma("unroll")                                                             \
    for(int p = 0; p < 4; ++p){                                                   \
      B0.u[p] = (unsigned)CUR[2*p]    | ((unsigned)CUR[2*p+1] << 16);             \
      B1.u[p] = (unsigned)CUR[8+2*p]  | ((unsigned)CUR[8+2*p+1] << 16);           \
      unsigned glo = (unsigned)CUR[16+2*p] | ((unsigned)CUR[16+2*p+1] << 16);     \
      unsigned llo = (unsigned)sh[b2b[2*p] + rowcs] |                             \
                     ((unsigned)sh[b2b[2*p+1] + rowcs] << 16);                    \
      B2.u[p] = glo | (llo & msk2[p]);                                            \
      B3.u[p] = (unsigned)sh[b2b[8+2*p]  + rowcs] |                               \
                ((unsigned)sh[b2b[8+2*p+1]  + rowcs] << 16);                      \
      B4.u[p] = (unsigned)sh[b2b[16+2*p] + rowcs] |                               \
                ((unsigned)sh[b2b[16+2*p+1] + rowcs] << 16);                      \
      B5.u[p] = ((unsigned)sh[b2b[24+2*p] + rowcs] |                              \
                 ((unsigned)sh[b2b[24+2*p+1] + rowcs] << 16)) & msk5[p];          \
    }                                                                             \
    __builtin_amdgcn_s_setprio(1);                                                \
    f32x4 acc = __builtin_amdgcn_mfma_f32_16x16x32_bf16(af[0], B0.v, cb, 0, 0, 0);\
    acc = __builtin_amdgcn_mfma_f32_16x16x32_bf16(af[1], B1.v, acc, 0, 0, 0);     \
    acc = __builtin_amdgcn_mfma_f32_16x16x32_bf16(af[2], B2.v, acc, 0, 0, 0);     \
    acc = __builtin_amdgcn_mfma_f32_16x16x32_bf16(af[3], B3.v, acc, 0, 0, 0);     \
    acc = __builtin_amdgcn_mfma_f32_16x16x32_bf16(af[4], B4.v, acc, 0, 0, 0);     \
    acc = __builtin_amdgcn_mfma_f32_16x16x32_bf16(af[5], B5.v, acc, 0, 0, 0);     \
    __builtin_amdgcn_s_setprio(0);                                                \
    _Pragma("unroll")                                                             \
    for(int r = 0; r < 4; ++r){                                                   \
      const int co = g * 4 + r;                                                   \
      if(co < 10)                                                                 \
        gout[outB + (unsigned)co * 1048576u + (unsigned)(hw * 1024) + s0 + n] =   \
            f2bf(fmaxf(acc[r], 0.f));                                             \
    }                                                                             \
    s0 += 16u;                                                                    \
  }

  for(int itp = 0; itp < 8; ++itp){
    CMM_STEP(ga, gb)
    CMM_STEP(gb, ga)
  }
#undef CMM_STEP
}

// ---------- fused dual-path conv layer L0 (VALU, r5-proven) + XCD swizzle ----------
template<int CI, typename TI, typename TO>
__global__ __launch_bounds__(128, 4) void conv12_k(
    const TI* __restrict__ in, TO* __restrict__ out,
    const float* __restrict__ wq, const float* __restrict__ wsp,
    const float* __restrict__ bq, const float* __restrict__ bsp,
    size_t in_pstride){
  __shared__ float P[18][36];
  const int tid = threadIdx.x;
  const int blk = ((blockIdx.x & 7) << 9) | (blockIdx.x >> 3);   // 4096 = 8 x 512
  const int path = blk >> 11;
  const int r0 = blk & 2047;
  const int strip = r0 & 1;
  const int hw = r0 >> 1;
  const int w = hw & 31, h = hw >> 5;
  const int lr = tid >> 3;
  const int c  = (tid & 7) * 4;
  const int own = hw * 1024 + strip * 512 + tid * 4;
  const int halo_src = hw * 1024 + (strip ? 15 * 32 : 16 * 32) + (tid & 7) * 4;
  const int hrow = strip ? 0 : 17;
  const float* wA = path ? wsp : wq;
  const float* wB = path ? wq : wsp;
  const TI* inp = in + (size_t)path * in_pstride;
  TO* outp = out + (size_t)path * 10485760;

  bool valid[9];
  #pragma unroll
  for(int dh = 0; dh < 3; ++dh)
    #pragma unroll
    for(int dw = 0; dw < 3; ++dw)
      valid[dh * 3 + dw] = ((unsigned)(h + dh - 1) < 32u) && ((unsigned)(w + dw - 1) < 32u);

  for(int i = tid; i < 18 * 36; i += 128) ((float*)P)[i] = 0.f;

  float acc[10][4];
  #pragma unroll
  for(int co = 0; co < 10; ++co){
    float bv = bq[co] + bsp[co];
    acc[co][0] = bv; acc[co][1] = bv; acc[co][2] = bv; acc[co][3] = bv;
  }

  for(int ci = 0; ci < CI; ++ci){
    const TI* base = inp + (size_t)ci * 1048576;
    float4 qv[9];
    #pragma unroll
    for(int dh = 0; dh < 3; ++dh){
      #pragma unroll
      for(int dw = 0; dw < 3; ++dw){
        const int t = dh * 3 + dw;
        float4 vv = make_float4(0.f, 0.f, 0.f, 0.f);
        if(valid[t]) vv = ld4(base + own + ((dh - 1) * 32 + (dw - 1)) * 1024);
        qv[t] = vv;
      }
    }
    float4 hv = make_float4(0.f, 0.f, 0.f, 0.f);
    if(tid < 8) hv = ld4(base + halo_src);

    __syncthreads();
    *(float4*)&P[1 + lr][c] = qv[4];
    if(tid < 8) *(float4*)&P[hrow][tid * 4] = hv;
    __syncthreads();

    float pr[3][6];
    #pragma unroll
    for(int k1 = 0; k1 < 3; ++k1){
      const float* row = &P[lr + k1][0];
      float4 mid = *(const float4*)(row + c);
      pr[k1][0] = row[c == 0 ? 32 : c - 1];
      pr[k1][1] = mid.x; pr[k1][2] = mid.y; pr[k1][3] = mid.z; pr[k1][4] = mid.w;
      pr[k1][5] = row[c + 4];
    }

    #pragma unroll
    for(int co = 0; co < 10; ++co){
      const float* wa = wA + (co * CI + ci) * 9;
      const float* wb = wB + (co * CI + ci) * 9;
      #pragma unroll
      for(int t = 0; t < 9; ++t){
        float wv = wa[t];
        acc[co][0] += wv * qv[t].x; acc[co][1] += wv * qv[t].y;
        acc[co][2] += wv * qv[t].z; acc[co][3] += wv * qv[t].w;
      }
      #pragma unroll
      for(int k1 = 0; k1 < 3; ++k1){
        #pragma unroll
        for(int k2 = 0; k2 < 3; ++k2){
          float wv = wb[k1 * 3 + k2];
          #pragma unroll
          for(int j = 0; j < 4; ++j) acc[co][j] += wv * pr[k1][k2 + j];
        }
      }
    }
  }

  #pragma unroll
  for(int co = 0; co < 10; ++co){
    float4 r;
    r.x = fmaxf(acc[co][0], 0.f); r.y = fmaxf(acc[co][1], 0.f);
    r.z = fmaxf(acc[co][2], 0.f); r.w = fmaxf(acc[co][3], 0.f);
    st4(outp + (size_t)co * 1048576 + own, r);
  }
}

// ---------- path-split last layer (CO=1): atomicAdd relu into zeroed y + XCD swizzle ----------
__global__ __launch_bounds__(128, 4) void conv3_k(
    const __hip_bfloat16* __restrict__ in,      // t2 base: [path][10][1M]
    const float* __restrict__ wq, const float* __restrict__ wsp,
    const float* __restrict__ bq, const float* __restrict__ bsp,
    float* __restrict__ yb){
  __shared__ float P[18][36];
  const int tid = threadIdx.x;
  const int blk = ((blockIdx.x & 7) << 9) | (blockIdx.x >> 3);   // 4096 = 8 x 512
  const int path = blk >> 11;
  const int r0 = blk & 2047;
  const int strip = r0 & 1;
  const int hw = r0 >> 1;
  const int w = hw & 31, h = hw >> 5;
  const int lr = tid >> 3;
  const int c  = (tid & 7) * 4;
  const int own = hw * 1024 + strip * 512 + tid * 4;
  const int halo_src = hw * 1024 + (strip ? 15 * 32 : 16 * 32) + (tid & 7) * 4;
  const int hrow = strip ? 0 : 17;
  const float* wA = path ? wsp : wq;
  const float* wB = path ? wq : wsp;
  const __hip_bfloat16* inp = in + (size_t)path * 10485760;

  bool valid[9];
  #pragma unroll
  for(int dh = 0; dh < 3; ++dh)
    #pragma unroll
    for(int dw = 0; dw < 3; ++dw)
      valid[dh * 3 + dw] = ((unsigned)(h + dh - 1) < 32u) && ((unsigned)(w + dw - 1) < 32u);

  for(int i = tid; i < 18 * 36; i += 128) ((float*)P)[i] = 0.f;

  float bv = bq[0] + bsp[0];
  float a0 = bv, a1 = bv, a2 = bv, a3 = bv;

  for(int ci = 0; ci < 10; ++ci){
    const __hip_bfloat16* base = inp + (size_t)ci * 1048576;
    float4 qv[9];
    #pragma unroll
    for(int dh = 0; dh < 3; ++dh){
      #pragma unroll
      for(int dw = 0; dw < 3; ++dw){
        const int t = dh * 3 + dw;
        float4 vv = make_float4(0.f, 0.f, 0.f, 0.f);
        if(valid[t]) vv = ld4(base + own + ((dh - 1) * 32 + (dw - 1)) * 1024);
        qv[t] = vv;
      }
    }
    float4 hv = make_float4(0.f, 0.f, 0.f, 0.f);
    if(tid < 8) hv = ld4(base + halo_src);

    __syncthreads();
    *(float4*)&P[1 + lr][c] = qv[4];
    if(tid < 8) *(float4*)&P[hrow][tid * 4] = hv;
    __syncthreads();

    float pr[3][6];
    #pragma unroll
    for(int k1 = 0; k1 < 3; ++k1){
      const float* row = &P[lr + k1][0];
      float4 mid = *(const float4*)(row + c);
      pr[k1][0] = row[c == 0 ? 32 : c - 1];
      pr[k1][1] = mid.x; pr[k1][2] = mid.y; pr[k1][3] = mid.z; pr[k1][4] = mid.w;
      pr[k1][5] = row[c + 4];
    }

    const float* wa = wA + ci * 9;
    const float* wb = wB + ci * 9;
    #pragma unroll
    for(int t = 0; t < 9; ++t){
      float wv = wa[t];
      a0 += wv * qv[t].x; a1 += wv * qv[t].y;
      a2 += wv * qv[t].z; a3 += wv * qv[t].w;
    }
    #pragma unroll
    for(int k1 = 0; k1 < 3; ++k1){
      #pragma unroll
      for(int k2 = 0; k2 < 3; ++k2){
        float wv = wb[k1 * 3 + k2];
        a0 += wv * pr[k1][k2 + 0];
        a1 += wv * pr[k1][k2 + 1];
        a2 += wv * pr[k1][k2 + 2];
        a3 += wv * pr[k1][k2 + 3];
      }
    }
  }

  atomicAdd(yb + own + 0, fmaxf(a0, 0.f));
  atomicAdd(yb + own + 1, fmaxf(a1, 0.f));
  atomicAdd(yb + own + 2, fmaxf(a2, 0.f));
  atomicAdd(yb + own + 3, fmaxf(a3, 0.f));
}

// ---------- mm2 + mask + softmax fused, one block per (b,q) row ----------
__global__ __launch_bounds__(256) void softmax_k(
    const float* __restrict__ y, const float* __restrict__ rmax,
    const unsigned* __restrict__ cbits, const void* __restrict__ mask,
    const int* __restrict__ mode, float* __restrict__ attn){
  int row = blockIdx.x;          // b*1024+q
  int b = row >> 10;
  int tid = threadIdx.x;
  int kc = tid * 4;
  float ra = rmax[row] + EPSF;
  float4 v = *(const float4*)(y + (size_t)row * 1024 + kc);
  int md = *mode;
  float vv[4] = {v.x, v.y, v.z, v.w};
  float s[4];
  #pragma unroll
  for(int j = 0; j < 4; ++j){
    int k = kc + j;
    float cb = fdec(cbits[(b << 10) + k]) + EPSF;
    float m = vv[j] * vv[j] * vv[j] / (ra * cb);
    bool msk;
    if(md == 0)      msk = ((const int*)mask)[(b << 10) + k] != 0;
    else if(md == 1) msk = ((const float*)mask)[(b << 10) + k] != 0.f;
    else             msk = ((const unsigned char*)mask)[(b << 10) + k] != 0;
    if(msk) m = 1e-4f;
    s[j] = m * TEMPF;
  }
  float mx = fmaxf(fmaxf(s[0], s[1]), fmaxf(s[2], s[3]));
  mx = blockMax256(mx);
  float e[4]; float sum = 0.f;
  #pragma unroll
  for(int j = 0; j < 4; ++j){ e[j] = expf(s[j] - mx); sum += e[j]; }
  sum = blockSum256(sum);
  float inv = 1.0f / sum;
  float4 o; o.x = e[0] * inv; o.y = e[1] * inv; o.z = e[2] * inv; o.w = e[3] * inv;
  *(float4*)(attn + (size_t)row * 1024 + kc) = o;
}

// ---------- partial[ks][b,c,q] = sum_{k in split ks} v[b,c,k]*attn[b,q,k] ----------
__global__ __launch_bounds__(256) void bmm_k(const float* __restrict__ v,
    const float* __restrict__ attn, float* __restrict__ part){
  __shared__ float At[64][68];
  __shared__ float Bt[64][68];
  int b  = blockIdx.y >> 2;
  int ks = blockIdx.y & 3;
  int ct = blockIdx.x >> 4, qt = blockIdx.x & 15;
  int tid = threadIdx.x;
  int c0 = ct * 64, q0 = qt * 64;
  int tx = tid & 15, ty = tid >> 4;
  float acc[4][4] = {};
  for(int k0 = ks * 256; k0 < ks * 256 + 256; k0 += 64){
    #pragma unroll
    for(int l = 0; l < 4; ++l){
      int r = (tid >> 4) + l * 16;
      int cc = (tid & 15) * 4;
      *(float4*)&At[r][cc] = *(const float4*)(v    + ((size_t)b * 256  + c0 + r) * 1024 + k0 + cc);
      *(float4*)&Bt[r][cc] = *(const float4*)(attn + ((size_t)b * 1024 + q0 + r) * 1024 + k0 + cc);
    }
    __syncthreads();
    #pragma unroll 4
    for(int kk = 0; kk < 64; ++kk){
      float a_[4], b_[4];
      #pragma unroll
      for(int i = 0; i < 4; ++i){ a_[i] = At[ty * 4 + i][kk]; b_[i] = Bt[tx * 4 + i][kk]; }
      #pragma unroll
      for(int i = 0; i < 4; ++i)
        #pragma unroll
        for(int j = 0; j < 4; ++j) acc[i][j] += a_[i] * b_[j];
    }
    __syncthreads();
  }
  float* pb = part + (size_t)ks * 1048576;
  #pragma unroll
  for(int i = 0; i < 4; ++i){
    float4 r; r.x = acc[i][0]; r.y = acc[i][1]; r.z = acc[i][2]; r.w = acc[i][3];
    *(float4*)(pb + ((size_t)b * 256 + c0 + ty * 4 + i) * 1024 + q0 + tx * 4) = r;
  }
}

__global__ __launch_bounds__(256) void bmmred_k(const float* __restrict__ part,
                                                float* __restrict__ out){
  int i = blockIdx.x * 256 + threadIdx.x;      // over 262144 float4
  const float4* p = (const float4*)part;
  float4 a = p[i], b = p[i + 262144], cc = p[i + 524288], d = p[i + 786432];
  float4 o;
  o.x = a.x + b.x + cc.x + d.x;
  o.y = a.y + b.y + cc.y + d.y;
  o.z = a.z + b.z + cc.z + d.z;
  o.w = a.w + b.w + cc.w + d.w;
  ((float4*)out)[i] = o;
}

extern "C" void kernel_launch(void* const* d_in, const int* in_sizes, int n_in,
                              void* d_out, int out_size, void* d_ws, size_t ws_size,
                              hipStream_t stream){
  (void)in_sizes; (void)n_in; (void)out_size; (void)ws_size;
  const float* corr = (const float*)d_in[0];
  const float* v    = (const float*)d_in[1];
  const void*  mask = d_in[2];
  const float* wq[3]  = {(const float*)d_in[3],  (const float*)d_in[7],  (const float*)d_in[11]};
  const float* bq[3]  = {(const float*)d_in[4],  (const float*)d_in[8],  (const float*)d_in[12]};
  const float* wsp[3] = {(const float*)d_in[5],  (const float*)d_in[9],  (const float*)d_in[13]};
  const float* bsp[3] = {(const float*)d_in[6],  (const float*)d_in[10], (const float*)d_in[14]};
  float* out = (float*)d_out;

  // ---- workspace layout: total exactly 117,571,584 B (proven fit) ----
  char* ws = (char*)d_ws;
  float* x0 = (float*)(ws);                      // 16.78 MB f32
  float* y  = (float*)(ws + 16777216);           // 16.78 MB f32
  char* aux = ws + 33554432;                     // 128 KiB
  float*    rmax1 = (float*)(aux);
  unsigned* cb1   = (unsigned*)(aux + 16384);
  float*    rmax2 = (float*)(aux + 32768);
  unsigned* cb2   = (unsigned*)(aux + 49152);
  int*      flag  = (int*)(aux + 65536);
  unsigned short* wp = (unsigned short*)(aux + 69632);  // 12,288 B
  float*          bs = (float*)(aux + 81920);          // 128 B
  unsigned* zeros = (unsigned*)(aux + 98304);          // 4,096 B zero stripe
  char* treg = ws + 33685504;                    // 2 x 41,943,040 B bf16 dual-path buffers
  __hip_bfloat16* t1 = (__hip_bfloat16*)(treg);                 // [path][10][1M]
  __hip_bfloat16* t2 = (__hip_bfloat16*)(treg + 41943040);
  float* attn = x0;
  float* part = (float*)treg;

  // u16-element offsets within ws (for convmm 32-bit addressing)
  const unsigned t1Elem   = 33685504u / 2u;
  const unsigned t2Elem   = 75628544u / 2u;
  const unsigned zeroElem = 33652736u / 2u;

  setup_k<<<4137, 256, 0, stream>>>((const unsigned*)mask, flag, cb1, cb2, zeros,
                                    wq[1], wsp[1], bq[1], bsp[1], wp, bs, (float4*)y);
  rcmax_k<<<4224, 256, 0, stream>>>(corr, rmax1, cb1);
  mmapply_k<<<4096, 256, 0, stream>>>(corr, rmax1, cb1, x0);

  for(int bb = 0; bb < 4; ++bb){
    const float* xb = x0 + (size_t)bb * 1048576;
    float*       yb = y  + (size_t)bb * 1048576;
    conv12_k<1, float, __hip_bfloat16><<<4096, 128, 0, stream>>>(
        xb, t1, wq[0], wsp[0], bq[0], bsp[0], 0);
    convmm_k<<<2048, 256, 0, stream>>>(
        (const unsigned short*)ws, (unsigned short*)ws, wp, bs, t1Elem, t2Elem, zeroElem);
    conv3_k<<<4096, 128, 0, stream>>>(
        t2, wq[2], wsp[2], bq[2], bsp[2], yb);
  }

  rcmax_k<<<4224, 256, 0, stream>>>(y, rmax2, cb2);
  softmax_k<<<4096, 256, 0, stream>>>(y, rmax2, cb2, mask, flag, attn);
  bmm_k<<<dim3(64, 16), 256, 0, stream>>>(v, attn, part);
  bmmred_k<<<1024, 256, 0, stream>>>(part, out);
}

// Round 17
// 680.295 us; speedup vs baseline: 1.1338x; 1.0254x over previous
//
#include <hip/hip_runtime.h>
#include <hip/hip_bf16.h>
#include <cstdint>

#define TEMPF 3.0f
#define EPSF 1e-5f

typedef __attribute__((ext_vector_type(8))) short bf16x8;
typedef __attribute__((ext_vector_type(4))) float f32x4;

// ---------- type helpers (f32 <-> bf16 staging) ----------
static __device__ __forceinline__ float bf2f(unsigned short u){
  union { unsigned u32; float f; } x; x.u32 = ((unsigned)u) << 16; return x.f;
}
static __device__ __forceinline__ unsigned short f2bf(float f){
  unsigned u = __float_as_uint(f);
  unsigned r = (u + 0x7fffu + ((u >> 16) & 1u)) >> 16;   // RNE
  return (unsigned short)r;
}
static __device__ __forceinline__ float4 ld4(const float* p){ return *(const float4*)p; }
static __device__ __forceinline__ float4 ld4(const __hip_bfloat16* p){
  ushort4 u = *(const ushort4*)p;
  return make_float4(bf2f(u.x), bf2f(u.y), bf2f(u.z), bf2f(u.w));
}
static __device__ __forceinline__ void st4(float* p, float4 v){ *(float4*)p = v; }
static __device__ __forceinline__ void st4(__hip_bfloat16* p, float4 v){
  *(ushort4*)p = make_ushort4(f2bf(v.x), f2bf(v.y), f2bf(v.z), f2bf(v.w));
}

// ---------- ordered-uint float encoding for atomic max ----------
static __device__ __forceinline__ unsigned fkey(float f){
  unsigned u = __float_as_uint(f);
  return (u & 0x80000000u) ? ~u : (u | 0x80000000u);
}
static __device__ __forceinline__ float fdec(unsigned k){
  return (k & 0x80000000u) ? __uint_as_float(k ^ 0x80000000u) : __uint_as_float(~k);
}

__device__ __forceinline__ float blockMax256(float v){
  __shared__ float red[4];
  #pragma unroll
  for(int off = 32; off; off >>= 1) v = fmaxf(v, __shfl_down(v, off));
  __syncthreads();
  if((threadIdx.x & 63) == 0) red[threadIdx.x >> 6] = v;
  __syncthreads();
  return fmaxf(fmaxf(red[0], red[1]), fmaxf(red[2], red[3]));
}
__device__ __forceinline__ float blockSum256(float v){
  __shared__ float red2[4];
  #pragma unroll
  for(int off = 32; off; off >>= 1) v += __shfl_down(v, off);
  __syncthreads();
  if((threadIdx.x & 63) == 0) red2[threadIdx.x >> 6] = v;
  __syncthreads();
  return red2[0] + red2[1] + red2[2] + red2[3];
}

// ---------- fused setup: zero y | detect mask dtype | wpack L1 | zero cb/zeros ----------
__global__ __launch_bounds__(256) void setup_k(
    const unsigned* __restrict__ mask, int* __restrict__ flag,
    unsigned* __restrict__ cb1, unsigned* __restrict__ cb2, unsigned* __restrict__ zeros,
    const float* __restrict__ wq1, const float* __restrict__ wsp1,
    const float* __restrict__ bq1, const float* __restrict__ bsp1,
    unsigned short* __restrict__ wp, float* __restrict__ bs,
    float4* __restrict__ y){
  const int b = blockIdx.x, tid = threadIdx.x;
  if(b < 4096){
    y[b * 256 + tid] = make_float4(0.f, 0.f, 0.f, 0.f);
  } else if(b == 4096){
    __shared__ int sa, sb;
    if(tid == 0){ sa = 0; sb = 0; }
    __syncthreads();
    int a = 0, b2 = 0;
    for(int i = tid; i < 1024; i += 256){
      unsigned w = mask[i];
      if(w != 0u && w != 1u) a = 1;
      if(w != 0u && w != 0x3f800000u) b2 = 1;
    }
    if(a)  atomicOr(&sa, 1);
    if(b2) atomicOr(&sb, 1);
    __syncthreads();
    if(tid == 0) *flag = (sa == 0) ? 0 : ((sb == 0) ? 1 : 2);  // 0=i32 1=f32 2=u8
  } else if(b < 4121){
    int i = (b - 4097) * 256 + tid;
    if(i < 6144){
      int path = i / 3072, rem = i % 3072, co = rem / 192, k = rem % 192;
      float v = 0.f;
      if(co < 10 && k < 180){
        const float* WA = path ? wsp1 : wq1;
        const float* WB = path ? wq1 : wsp1;
        int kk = k < 90 ? k : k - 90;
        int ci = kk / 9, t = kk % 9;
        v = (k < 90 ? WA : WB)[(co * 10 + ci) * 9 + t];
      }
      wp[i] = f2bf(v);
    }
    if(i < 32){
      int co = i & 15;
      bs[i] = co < 10 ? bq1[co] + bsp1[co] : 0.f;
    }
  } else {
    int i = (b - 4121) * 256 + tid;
    if(i < 4096){ cb1[i] = 0u; cb2[i] = 0u; }
    if(i < 1024) zeros[i] = 0u;
  }
}

// ---------- fused row max + col max ----------
__global__ __launch_bounds__(256) void rcmax_k(const float* __restrict__ x,
    float* __restrict__ rmax, unsigned* __restrict__ cbits){
  const int b = blockIdx.x, tid = threadIdx.x;
  if(b < 4096){
    float4 v = *(const float4*)(x + (size_t)b * 1024 + tid * 4);
    float m = fmaxf(fmaxf(v.x, v.y), fmaxf(v.z, v.w));
    m = blockMax256(m);
    if(tid == 0) rmax[b] = m;
  } else {
    int blk = b - 4096;
    int bb = blk >> 5, rg = blk & 31;
    const float* base = x + (size_t)bb * 1048576 + (size_t)rg * 32 * 1024;
    int col = tid * 4;
    float4 m = make_float4(-1e30f, -1e30f, -1e30f, -1e30f);
    for(int r = 0; r < 32; ++r){
      float4 v = *(const float4*)(base + r * 1024 + col);
      m.x = fmaxf(m.x, v.x); m.y = fmaxf(m.y, v.y);
      m.z = fmaxf(m.z, v.z); m.w = fmaxf(m.w, v.w);
    }
    unsigned* cb = cbits + (bb << 10) + col;
    atomicMax(cb + 0, fkey(m.x)); atomicMax(cb + 1, fkey(m.y));
    atomicMax(cb + 2, fkey(m.z)); atomicMax(cb + 3, fkey(m.w));
  }
}

// ---------- mutual matching elementwise ----------
__global__ __launch_bounds__(256) void mmapply_k(const float* __restrict__ x,
    const float* __restrict__ rmax, const unsigned* __restrict__ cbits,
    float* __restrict__ out){
  int idx4 = blockIdx.x * 256 + threadIdx.x;
  int b = idx4 >> 18;
  int rem = idx4 & 262143;
  int q = rem >> 8;
  int k = (rem & 255) * 4;
  float4 v = ((const float4*)x)[idx4];
  float ra = rmax[(b << 10) + q] + EPSF;
  const unsigned* cb = cbits + (b << 10) + k;
  float4 o;
  o.x = v.x * v.x * v.x / (ra * (fdec(cb[0]) + EPSF));
  o.y = v.y * v.y * v.y / (ra * (fdec(cb[1]) + EPSF));
  o.z = v.z * v.z * v.z / (ra * (fdec(cb[2]) + EPSF));
  o.w = v.w * v.w * v.w / (ra * (fdec(cb[3]) + EPSF));
  ((float4*)out)[idx4] = o;
}

// ---------- MFMA implicit-GEMM L1: r14 structure + byte-offset addressing diet ----------
// Identical load/pack/MFMA flow to the 91us r14 kernel; only address math changed:
// b1i/store bases are BYTE offsets (no per-load shifts, no 64-bit rebuilds),
// rowcs advanced incrementally (+16/+24 alternation).
__global__ __launch_bounds__(256)
void convmm_k(const unsigned short* __restrict__ gin, unsigned short* __restrict__ gout,
              const unsigned short* __restrict__ wpack, const float* __restrict__ bias,
              unsigned inElem, unsigned outElem, unsigned zeroElem){
  __shared__ unsigned short sh[13600];          // [ci][34 rows][40 cols]
  const int tid = threadIdx.x;
  const int blk = ((blockIdx.x & 7) << 8) | (blockIdx.x >> 3);   // 2048 = 8 x 256
  const int path = blk >> 10;
  const int hw = blk & 1023;
  const int h = hw >> 5, w = hw & 31;
  const unsigned inB = inElem + (unsigned)path * 10485760u;
  const unsigned outB = outElem + (unsigned)path * 10485760u;

  for(int i = tid; i < 6800; i += 256) ((unsigned*)sh)[i] = 0u;
  __syncthreads();
  for(int idx = tid; idx < 2560; idx += 256){
    int ci = idx >> 8, s = (idx & 255) * 4;
    ushort4 v = *(const ushort4*)(gin + inB + ci * 1048576 + hw * 1024 + s);
    *(ushort4*)(sh + ci * 1360 + (1 + (s >> 5)) * 40 + 4 + (s & 31)) = v;
  }
  __syncthreads();

  const int l = tid & 63, wv = tid >> 6;
  const int g = l >> 4, n = l & 15;

  bf16x8 af[6];
  #pragma unroll
  for(int sl = 0; sl < 6; ++sl)
    af[sl] = *(const bf16x8*)(wpack + ((size_t)path * 16 + n) * 192 + sl * 32 + g * 8);
  f32x4 cb = *(const f32x4*)(bias + path * 16 + g * 4);

  unsigned b1i[24]; unsigned b2b[32]; unsigned msk2[4], msk5[4];
  const unsigned s0 = (unsigned)wv * 256u;
  #pragma unroll
  for(int gg = 0; gg < 4; ++gg){
    if(g == gg){
      #pragma unroll
      for(int sl = 0; sl < 3; ++sl){
        #pragma unroll
        for(int j = 0; j < 8; ++j){
          const int k = sl * 32 + gg * 8 + j;
          unsigned v = zeroElem;
          if(k < 90){
            const int ci = k / 9, t = k % 9;
            const int hh = h + t / 3 - 1, ww = w + t % 3 - 1;
            if((unsigned)hh < 32u && (unsigned)ww < 32u)
              v = inB + (unsigned)ci * 1048576u + (unsigned)((hh * 32 + ww) * 1024) + (unsigned)n;
          }
          b1i[sl * 8 + j] = (v + s0) * 2u;       // BYTE offset
        }
      }
      #pragma unroll
      for(int sl = 2; sl < 6; ++sl){
        #pragma unroll
        for(int j = 0; j < 8; ++j){
          const int k = sl * 32 + gg * 8 + j;
          const int kp = (k >= 90 && k < 180) ? (k - 90) : 0;
          const int ci = kp / 9, t = kp % 9;
          b2b[(sl - 2) * 8 + j] = (unsigned)(ci * 1360 + (t / 3) * 40 + 3 + (t % 3) + n);
        }
      }
      #pragma unroll
      for(int p = 0; p < 4; ++p){
        const int ka = 64 + gg * 8 + 2 * p, kb = ka + 1;
        msk2[p] = ((ka >= 90) ? 0xFFFFu : 0u) | ((kb >= 90) ? 0xFFFF0000u : 0u);
        const int kc = 160 + gg * 8 + 2 * p, kd = kc + 1;
        msk5[p] = ((kc < 180) ? 0xFFFFu : 0u) | ((kd < 180) ? 0xFFFF0000u : 0u);
      }
    }
  }

  // store byte-offset bases (advance +32 B/step); co>=10 lanes never store
  unsigned sb[4]; bool sv[4];
  #pragma unroll
  for(int r = 0; r < 4; ++r){
    const int co = g * 4 + r;
    sv[r] = (co < 10);
    sb[r] = (outB + (unsigned)co * 1048576u + (unsigned)(hw * 1024) + s0 + (unsigned)n) * 2u;
  }
  unsigned rowcs = (s0 >> 5) * 40u;             // s0&16 == 0 at init

  const char* ginc = (const char*)gin;
  char* goutc = (char*)gout;

  // prologue: prefetch iteration 0's gathers
  unsigned short ga[24], gb[24];
  #pragma unroll
  for(int m = 0; m < 24; ++m) ga[m] = *(const unsigned short*)(ginc + b1i[m]);
  #pragma unroll
  for(int m = 0; m < 24; ++m) b1i[m] += 32u;

#define CMM_STEP(CUR, NXT, RDELTA)                                                \
  {                                                                               \
    _Pragma("unroll")                                                             \
    for(int m = 0; m < 24; ++m) NXT[m] = *(const unsigned short*)(ginc + b1i[m]); \
    _Pragma("unroll")                                                             \
    for(int m = 0; m < 24; ++m) b1i[m] += 32u;                                    \
    union { unsigned u[4]; bf16x8 v; } B0, B1, B2, B3, B4, B5;                    \
    _Pragma("unroll")                                                             \
    for(int p = 0; p < 4; ++p){                                                   \
      B0.u[p] = (unsigned)CUR[2*p]    | ((unsigned)CUR[2*p+1] << 16);             \
      B1.u[p] = (unsigned)CUR[8+2*p]  | ((unsigned)CUR[8+2*p+1] << 16);           \
      unsigned glo = (unsigned)CUR[16+2*p] | ((unsigned)CUR[16+2*p+1] << 16);     \
      unsigned llo = (unsigned)sh[b2b[2*p] + rowcs] |                             \
                     ((unsigned)sh[b2b[2*p+1] + rowcs] << 16);                    \
      B2.u[p] = glo | (llo & msk2[p]);                                            \
      B3.u[p] = (unsigned)sh[b2b[8+2*p]  + rowcs] |                               \
                ((unsigned)sh[b2b[8+2*p+1]  + rowcs] << 16);                      \
      B4.u[p] = (unsigned)sh[b2b[16+2*p] + rowcs] |                               \
                ((unsigned)sh[b2b[16+2*p+1] + rowcs] << 16);                      \
      B5.u[p] = ((unsigned)sh[b2b[24+2*p] + rowcs] |                              \
                 ((unsigned)sh[b2b[24+2*p+1] + rowcs] << 16)) & msk5[p];          \
    }                                                                             \
    rowcs += (RDELTA);                                                            \
    __builtin_amdgcn_s_setprio(1);                                                \
    f32x4 acc = __builtin_amdgcn_mfma_f32_16x16x32_bf16(af[0], B0.v, cb, 0, 0, 0);\
    acc = __builtin_amdgcn_mfma_f32_16x16x32_bf16(af[1], B1.v, acc, 0, 0, 0);     \
    acc = __builtin_amdgcn_mfma_f32_16x16x32_bf16(af[2], B2.v, acc, 0, 0, 0);     \
    acc = __builtin_amdgcn_mfma_f32_16x16x32_bf16(af[3], B3.v, acc, 0, 0, 0);     \
    acc = __builtin_amdgcn_mfma_f32_16x16x32_bf16(af[4], B4.v, acc, 0, 0, 0);     \
    acc = __builtin_amdgcn_mfma_f32_16x16x32_bf16(af[5], B5.v, acc, 0, 0, 0);     \
    __builtin_amdgcn_s_setprio(0);                                                \
    _Pragma("unroll")                                                             \
    for(int r = 0; r < 4; ++r){                                                   \
      if(sv[r])                                                                   \
        *(unsigned short*)(goutc + sb[r]) = f2bf(fmaxf(acc[r], 0.f));             \
    }                                                                             \
    _Pragma("unroll")                                                             \
    for(int r = 0; r < 4; ++r) sb[r] += 32u;                                      \
  }

  for(int itp = 0; itp < 8; ++itp){
    CMM_STEP(ga, gb, 16u)
    CMM_STEP(gb, ga, 24u)
  }
#undef CMM_STEP
}

// ---------- fused dual-path conv layer L0 (VALU, r5-proven) + XCD swizzle ----------
template<int CI, typename TI, typename TO>
__global__ __launch_bounds__(128, 4) void conv12_k(
    const TI* __restrict__ in, TO* __restrict__ out,
    const float* __restrict__ wq, const float* __restrict__ wsp,
    const float* __restrict__ bq, const float* __restrict__ bsp,
    size_t in_pstride){
  __shared__ float P[18][36];
  const int tid = threadIdx.x;
  const int blk = ((blockIdx.x & 7) << 9) | (blockIdx.x >> 3);   // 4096 = 8 x 512
  const int path = blk >> 11;
  const int r0 = blk & 2047;
  const int strip = r0 & 1;
  const int hw = r0 >> 1;
  const int w = hw & 31, h = hw >> 5;
  const int lr = tid >> 3;
  const int c  = (tid & 7) * 4;
  const int own = hw * 1024 + strip * 512 + tid * 4;
  const int halo_src = hw * 1024 + (strip ? 15 * 32 : 16 * 32) + (tid & 7) * 4;
  const int hrow = strip ? 0 : 17;
  const float* wA = path ? wsp : wq;
  const float* wB = path ? wq : wsp;
  const TI* inp = in + (size_t)path * in_pstride;
  TO* outp = out + (size_t)path * 10485760;

  bool valid[9];
  #pragma unroll
  for(int dh = 0; dh < 3; ++dh)
    #pragma unroll
    for(int dw = 0; dw < 3; ++dw)
      valid[dh * 3 + dw] = ((unsigned)(h + dh - 1) < 32u) && ((unsigned)(w + dw - 1) < 32u);

  for(int i = tid; i < 18 * 36; i += 128) ((float*)P)[i] = 0.f;

  float acc[10][4];
  #pragma unroll
  for(int co = 0; co < 10; ++co){
    float bv = bq[co] + bsp[co];
    acc[co][0] = bv; acc[co][1] = bv; acc[co][2] = bv; acc[co][3] = bv;
  }

  for(int ci = 0; ci < CI; ++ci){
    const TI* base = inp + (size_t)ci * 1048576;
    float4 qv[9];
    #pragma unroll
    for(int dh = 0; dh < 3; ++dh){
      #pragma unroll
      for(int dw = 0; dw < 3; ++dw){
        const int t = dh * 3 + dw;
        float4 vv = make_float4(0.f, 0.f, 0.f, 0.f);
        if(valid[t]) vv = ld4(base + own + ((dh - 1) * 32 + (dw - 1)) * 1024);
        qv[t] = vv;
      }
    }
    float4 hv = make_float4(0.f, 0.f, 0.f, 0.f);
    if(tid < 8) hv = ld4(base + halo_src);

    __syncthreads();
    *(float4*)&P[1 + lr][c] = qv[4];
    if(tid < 8) *(float4*)&P[hrow][tid * 4] = hv;
    __syncthreads();

    float pr[3][6];
    #pragma unroll
    for(int k1 = 0; k1 < 3; ++k1){
      const float* row = &P[lr + k1][0];
      float4 mid = *(const float4*)(row + c);
      pr[k1][0] = row[c == 0 ? 32 : c - 1];
      pr[k1][1] = mid.x; pr[k1][2] = mid.y; pr[k1][3] = mid.z; pr[k1][4] = mid.w;
      pr[k1][5] = row[c + 4];
    }

    #pragma unroll
    for(int co = 0; co < 10; ++co){
      const float* wa = wA + (co * CI + ci) * 9;
      const float* wb = wB + (co * CI + ci) * 9;
      #pragma unroll
      for(int t = 0; t < 9; ++t){
        float wv = wa[t];
        acc[co][0] += wv * qv[t].x; acc[co][1] += wv * qv[t].y;
        acc[co][2] += wv * qv[t].z; acc[co][3] += wv * qv[t].w;
      }
      #pragma unroll
      for(int k1 = 0; k1 < 3; ++k1){
        #pragma unroll
        for(int k2 = 0; k2 < 3; ++k2){
          float wv = wb[k1 * 3 + k2];
          #pragma unroll
          for(int j = 0; j < 4; ++j) acc[co][j] += wv * pr[k1][k2 + j];
        }
      }
    }
  }

  #pragma unroll
  for(int co = 0; co < 10; ++co){
    float4 r;
    r.x = fmaxf(acc[co][0], 0.f); r.y = fmaxf(acc[co][1], 0.f);
    r.z = fmaxf(acc[co][2], 0.f); r.w = fmaxf(acc[co][3], 0.f);
    st4(outp + (size_t)co * 1048576 + own, r);
  }
}

// ---------- path-split last layer (CO=1): atomicAdd relu into zeroed y + XCD swizzle ----------
__global__ __launch_bounds__(128, 4) void conv3_k(
    const __hip_bfloat16* __restrict__ in,      // t2 base: [path][10][1M]
    const float* __restrict__ wq, const float* __restrict__ wsp,
    const float* __restrict__ bq, const float* __restrict__ bsp,
    float* __restrict__ yb){
  __shared__ float P[18][36];
  const int tid = threadIdx.x;
  const int blk = ((blockIdx.x & 7) << 9) | (blockIdx.x >> 3);   // 4096 = 8 x 512
  const int path = blk >> 11;
  const int r0 = blk & 2047;
  const int strip = r0 & 1;
  const int hw = r0 >> 1;
  const int w = hw & 31, h = hw >> 5;
  const int lr = tid >> 3;
  const int c  = (tid & 7) * 4;
  const int own = hw * 1024 + strip * 512 + tid * 4;
  const int halo_src = hw * 1024 + (strip ? 15 * 32 : 16 * 32) + (tid & 7) * 4;
  const int hrow = strip ? 0 : 17;
  const float* wA = path ? wsp : wq;
  const float* wB = path ? wq : wsp;
  const __hip_bfloat16* inp = in + (size_t)path * 10485760;

  bool valid[9];
  #pragma unroll
  for(int dh = 0; dh < 3; ++dh)
    #pragma unroll
    for(int dw = 0; dw < 3; ++dw)
      valid[dh * 3 + dw] = ((unsigned)(h + dh - 1) < 32u) && ((unsigned)(w + dw - 1) < 32u);

  for(int i = tid; i < 18 * 36; i += 128) ((float*)P)[i] = 0.f;

  float bv = bq[0] + bsp[0];
  float a0 = bv, a1 = bv, a2 = bv, a3 = bv;

  for(int ci = 0; ci < 10; ++ci){
    const __hip_bfloat16* base = inp + (size_t)ci * 1048576;
    float4 qv[9];
    #pragma unroll
    for(int dh = 0; dh < 3; ++dh){
      #pragma unroll
      for(int dw = 0; dw < 3; ++dw){
        const int t = dh * 3 + dw;
        float4 vv = make_float4(0.f, 0.f, 0.f, 0.f);
        if(valid[t]) vv = ld4(base + own + ((dh - 1) * 32 + (dw - 1)) * 1024);
        qv[t] = vv;
      }
    }
    float4 hv = make_float4(0.f, 0.f, 0.f, 0.f);
    if(tid < 8) hv = ld4(base + halo_src);

    __syncthreads();
    *(float4*)&P[1 + lr][c] = qv[4];
    if(tid < 8) *(float4*)&P[hrow][tid * 4] = hv;
    __syncthreads();

    float pr[3][6];
    #pragma unroll
    for(int k1 = 0; k1 < 3; ++k1){
      const float* row = &P[lr + k1][0];
      float4 mid = *(const float4*)(row + c);
      pr[k1][0] = row[c == 0 ? 32 : c - 1];
      pr[k1][1] = mid.x; pr[k1][2] = mid.y; pr[k1][3] = mid.z; pr[k1][4] = mid.w;
      pr[k1][5] = row[c + 4];
    }

    const float* wa = wA + ci * 9;
    const float* wb = wB + ci * 9;
    #pragma unroll
    for(int t = 0; t < 9; ++t){
      float wv = wa[t];
      a0 += wv * qv[t].x; a1 += wv * qv[t].y;
      a2 += wv * qv[t].z; a3 += wv * qv[t].w;
    }
    #pragma unroll
    for(int k1 = 0; k1 < 3; ++k1){
      #pragma unroll
      for(int k2 = 0; k2 < 3; ++k2){
        float wv = wb[k1 * 3 + k2];
        a0 += wv * pr[k1][k2 + 0];
        a1 += wv * pr[k1][k2 + 1];
        a2 += wv * pr[k1][k2 + 2];
        a3 += wv * pr[k1][k2 + 3];
      }
    }
  }

  atomicAdd(yb + own + 0, fmaxf(a0, 0.f));
  atomicAdd(yb + own + 1, fmaxf(a1, 0.f));
  atomicAdd(yb + own + 2, fmaxf(a2, 0.f));
  atomicAdd(yb + own + 3, fmaxf(a3, 0.f));
}

// ---------- mm2 + mask + softmax fused, one block per (b,q) row ----------
__global__ __launch_bounds__(256) void softmax_k(
    const float* __restrict__ y, const float* __restrict__ rmax,
    const unsigned* __restrict__ cbits, const void* __restrict__ mask,
    const int* __restrict__ mode, float* __restrict__ attn){
  int row = blockIdx.x;          // b*1024+q
  int b = row >> 10;
  int tid = threadIdx.x;
  int kc = tid * 4;
  float ra = rmax[row] + EPSF;
  float4 v = *(const float4*)(y + (size_t)row * 1024 + kc);
  int md = *mode;
  float vv[4] = {v.x, v.y, v.z, v.w};
  float s[4];
  #pragma unroll
  for(int j = 0; j < 4; ++j){
    int k = kc + j;
    float cb = fdec(cbits[(b << 10) + k]) + EPSF;
    float m = vv[j] * vv[j] * vv[j] / (ra * cb);
    bool msk;
    if(md == 0)      msk = ((const int*)mask)[(b << 10) + k] != 0;
    else if(md == 1) msk = ((const float*)mask)[(b << 10) + k] != 0.f;
    else             msk = ((const unsigned char*)mask)[(b << 10) + k] != 0;
    if(msk) m = 1e-4f;
    s[j] = m * TEMPF;
  }
  float mx = fmaxf(fmaxf(s[0], s[1]), fmaxf(s[2], s[3]));
  mx = blockMax256(mx);
  float e[4]; float sum = 0.f;
  #pragma unroll
  for(int j = 0; j < 4; ++j){ e[j] = expf(s[j] - mx); sum += e[j]; }
  sum = blockSum256(sum);
  float inv = 1.0f / sum;
  float4 o; o.x = e[0] * inv; o.y = e[1] * inv; o.z = e[2] * inv; o.w = e[3] * inv;
  *(float4*)(attn + (size_t)row * 1024 + kc) = o;
}

// ---------- partial[ks][b,c,q] = sum_{k in split ks} v[b,c,k]*attn[b,q,k] ----------
__global__ __launch_bounds__(256) void bmm_k(const float* __restrict__ v,
    const float* __restrict__ attn, float* __restrict__ part){
  __shared__ float At[64][68];
  __shared__ float Bt[64][68];
  int b  = blockIdx.y >> 2;
  int ks = blockIdx.y & 3;
  int ct = blockIdx.x >> 4, qt = blockIdx.x & 15;
  int tid = threadIdx.x;
  int c0 = ct * 64, q0 = qt * 64;
  int tx = tid & 15, ty = tid >> 4;
  float acc[4][4] = {};
  for(int k0 = ks * 256; k0 < ks * 256 + 256; k0 += 64){
    #pragma unroll
    for(int l = 0; l < 4; ++l){
      int r = (tid >> 4) + l * 16;
      int cc = (tid & 15) * 4;
      *(float4*)&At[r][cc] = *(const float4*)(v    + ((size_t)b * 256  + c0 + r) * 1024 + k0 + cc);
      *(float4*)&Bt[r][cc] = *(const float4*)(attn + ((size_t)b * 1024 + q0 + r) * 1024 + k0 + cc);
    }
    __syncthreads();
    #pragma unroll 4
    for(int kk = 0; kk < 64; ++kk){
      float a_[4], b_[4];
      #pragma unroll
      for(int i = 0; i < 4; ++i){ a_[i] = At[ty * 4 + i][kk]; b_[i] = Bt[tx * 4 + i][kk]; }
      #pragma unroll
      for(int i = 0; i < 4; ++i)
        #pragma unroll
        for(int j = 0; j < 4; ++j) acc[i][j] += a_[i] * b_[j];
    }
    __syncthreads();
  }
  float* pb = part + (size_t)ks * 1048576;
  #pragma unroll
  for(int i = 0; i < 4; ++i){
    float4 r; r.x = acc[i][0]; r.y = acc[i][1]; r.z = acc[i][2]; r.w = acc[i][3];
    *(float4*)(pb + ((size_t)b * 256 + c0 + ty * 4 + i) * 1024 + q0 + tx * 4) = r;
  }
}

__global__ __launch_bounds__(256) void bmmred_k(const float* __restrict__ part,
                                                float* __restrict__ out){
  int i = blockIdx.x * 256 + threadIdx.x;      // over 262144 float4
  const float4* p = (const float4*)part;
  float4 a = p[i], b = p[i + 262144], cc = p[i + 524288], d = p[i + 786432];
  float4 o;
  o.x = a.x + b.x + cc.x + d.x;
  o.y = a.y + b.y + cc.y + d.y;
  o.z = a.z + b.z + cc.z + d.z;
  o.w = a.w + b.w + cc.w + d.w;
  ((float4*)out)[i] = o;
}

extern "C" void kernel_launch(void* const* d_in, const int* in_sizes, int n_in,
                              void* d_out, int out_size, void* d_ws, size_t ws_size,
                              hipStream_t stream){
  (void)in_sizes; (void)n_in; (void)out_size; (void)ws_size;
  const float* corr = (const float*)d_in[0];
  const float* v    = (const float*)d_in[1];
  const void*  mask = d_in[2];
  const float* wq[3]  = {(const float*)d_in[3],  (const float*)d_in[7],  (const float*)d_in[11]};
  const float* bq[3]  = {(const float*)d_in[4],  (const float*)d_in[8],  (const float*)d_in[12]};
  const float* wsp[3] = {(const float*)d_in[5],  (const float*)d_in[9],  (const float*)d_in[13]};
  const float* bsp[3] = {(const float*)d_in[6],  (const float*)d_in[10], (const float*)d_in[14]};
  float* out = (float*)d_out;

  // ---- workspace layout: total exactly 117,571,584 B (proven fit) ----
  char* ws = (char*)d_ws;
  float* x0 = (float*)(ws);                      // 16.78 MB f32
  float* y  = (float*)(ws + 16777216);           // 16.78 MB f32
  char* aux = ws + 33554432;                     // 128 KiB
  float*    rmax1 = (float*)(aux);
  unsigned* cb1   = (unsigned*)(aux + 16384);
  float*    rmax2 = (float*)(aux + 32768);
  unsigned* cb2   = (unsigned*)(aux + 49152);
  int*      flag  = (int*)(aux + 65536);
  unsigned short* wp = (unsigned short*)(aux + 69632);  // 12,288 B
  float*          bs = (float*)(aux + 81920);          // 128 B
  unsigned* zeros = (unsigned*)(aux + 98304);          // 4,096 B zero stripe
  char* treg = ws + 33685504;                    // 2 x 41,943,040 B bf16 dual-path buffers
  __hip_bfloat16* t1 = (__hip_bfloat16*)(treg);                 // [path][10][1M]
  __hip_bfloat16* t2 = (__hip_bfloat16*)(treg + 41943040);
  float* attn = x0;
  float* part = (float*)treg;

  // u16-element offsets within ws (for convmm 32-bit addressing)
  const unsigned t1Elem   = 33685504u / 2u;
  const unsigned t2Elem   = 75628544u / 2u;
  const unsigned zeroElem = 33652736u / 2u;

  setup_k<<<4137, 256, 0, stream>>>((const unsigned*)mask, flag, cb1, cb2, zeros,
                                    wq[1], wsp[1], bq[1], bsp[1], wp, bs, (float4*)y);
  rcmax_k<<<4224, 256, 0, stream>>>(corr, rmax1, cb1);
  mmapply_k<<<4096, 256, 0, stream>>>(corr, rmax1, cb1, x0);

  for(int bb = 0; bb < 4; ++bb){
    const float* xb = x0 + (size_t)bb * 1048576;
    float*       yb = y  + (size_t)bb * 1048576;
    conv12_k<1, float, __hip_bfloat16><<<4096, 128, 0, stream>>>(
        xb, t1, wq[0], wsp[0], bq[0], bsp[0], 0);
    convmm_k<<<2048, 256, 0, stream>>>(
        (const unsigned short*)ws, (unsigned short*)ws, wp, bs, t1Elem, t2Elem, zeroElem);
    conv3_k<<<4096, 128, 0, stream>>>(
        t2, wq[2], wsp[2], bq[2], bsp[2], yb);
  }

  rcmax_k<<<4224, 256, 0, stream>>>(y, rmax2, cb2);
  softmax_k<<<4096, 256, 0, stream>>>(y, rmax2, cb2, mask, flag, attn);
  bmm_k<<<dim3(64, 16), 256, 0, stream>>>(v, attn, part);
  bmmred_k<<<1024, 256, 0, stream>>>(part, out);
}

// Round 18
// 619.494 us; speedup vs baseline: 1.2450x; 1.0981x over previous
//
#include <hip/hip_runtime.h>
#include <hip/hip_bf16.h>
#include <cstdint>

#define TEMPF 3.0f
#define EPSF 1e-5f

typedef __attribute__((ext_vector_type(8))) short bf16x8;
typedef __attribute__((ext_vector_type(4))) float f32x4;

// ---------- type helpers (f32 <-> bf16 staging) ----------
static __device__ __forceinline__ float bf2f(unsigned short u){
  union { unsigned u32; float f; } x; x.u32 = ((unsigned)u) << 16; return x.f;
}
static __device__ __forceinline__ unsigned short f2bf(float f){
  unsigned u = __float_as_uint(f);
  unsigned r = (u + 0x7fffu + ((u >> 16) & 1u)) >> 16;   // RNE
  return (unsigned short)r;
}
static __device__ __forceinline__ float4 ld4(const float* p){ return *(const float4*)p; }
static __device__ __forceinline__ float4 ld4(const __hip_bfloat16* p){
  ushort4 u = *(const ushort4*)p;
  return make_float4(bf2f(u.x), bf2f(u.y), bf2f(u.z), bf2f(u.w));
}
static __device__ __forceinline__ void st4(float* p, float4 v){ *(float4*)p = v; }
static __device__ __forceinline__ void st4(__hip_bfloat16* p, float4 v){
  *(ushort4*)p = make_ushort4(f2bf(v.x), f2bf(v.y), f2bf(v.z), f2bf(v.w));
}

// ---------- ordered-uint float encoding for atomic max ----------
static __device__ __forceinline__ unsigned fkey(float f){
  unsigned u = __float_as_uint(f);
  return (u & 0x80000000u) ? ~u : (u | 0x80000000u);
}
static __device__ __forceinline__ float fdec(unsigned k){
  return (k & 0x80000000u) ? __uint_as_float(k ^ 0x80000000u) : __uint_as_float(~k);
}

__device__ __forceinline__ float blockMax256(float v){
  __shared__ float red[4];
  #pragma unroll
  for(int off = 32; off; off >>= 1) v = fmaxf(v, __shfl_down(v, off));
  __syncthreads();
  if((threadIdx.x & 63) == 0) red[threadIdx.x >> 6] = v;
  __syncthreads();
  return fmaxf(fmaxf(red[0], red[1]), fmaxf(red[2], red[3]));
}
__device__ __forceinline__ float blockSum256(float v){
  __shared__ float red2[4];
  #pragma unroll
  for(int off = 32; off; off >>= 1) v += __shfl_down(v, off);
  __syncthreads();
  if((threadIdx.x & 63) == 0) red2[threadIdx.x >> 6] = v;
  __syncthreads();
  return red2[0] + red2[1] + red2[2] + red2[3];
}

// ---------- fused setup: detect mask dtype | wpack L1 | zero cb/zeros (grid 41) ----------
__global__ __launch_bounds__(256) void setup_k(
    const unsigned* __restrict__ mask, int* __restrict__ flag,
    unsigned* __restrict__ cb1, unsigned* __restrict__ cb2, unsigned* __restrict__ zeros,
    const float* __restrict__ wq1, const float* __restrict__ wsp1,
    const float* __restrict__ bq1, const float* __restrict__ bsp1,
    unsigned short* __restrict__ wp, float* __restrict__ bs){
  const int b = blockIdx.x, tid = threadIdx.x;
  if(b == 0){
    __shared__ int sa, sb;
    if(tid == 0){ sa = 0; sb = 0; }
    __syncthreads();
    int a = 0, b2 = 0;
    for(int i = tid; i < 1024; i += 256){
      unsigned w = mask[i];
      if(w != 0u && w != 1u) a = 1;
      if(w != 0u && w != 0x3f800000u) b2 = 1;
    }
    if(a)  atomicOr(&sa, 1);
    if(b2) atomicOr(&sb, 1);
    __syncthreads();
    if(tid == 0) *flag = (sa == 0) ? 0 : ((sb == 0) ? 1 : 2);  // 0=i32 1=f32 2=u8
  } else if(b < 25){
    int i = (b - 1) * 256 + tid;
    if(i < 6144){
      int path = i / 3072, rem = i % 3072, co = rem / 192, k = rem % 192;
      float v = 0.f;
      if(co < 10 && k < 180){
        const float* WA = path ? wsp1 : wq1;
        const float* WB = path ? wq1 : wsp1;
        int kk = k < 90 ? k : k - 90;
        int ci = kk / 9, t = kk % 9;
        v = (k < 90 ? WA : WB)[(co * 10 + ci) * 9 + t];
      }
      wp[i] = f2bf(v);
    }
    if(i < 32){
      int co = i & 15;
      bs[i] = co < 10 ? bq1[co] + bsp1[co] : 0.f;
    }
  } else {
    int i = (b - 25) * 256 + tid;
    if(i < 4096){ cb1[i] = 0u; cb2[i] = 0u; }
    if(i < 1024) zeros[i] = 0u;
  }
}

// ---------- fused row max + col max (single input) ----------
__global__ __launch_bounds__(256) void rcmax_k(const float* __restrict__ x,
    float* __restrict__ rmax, unsigned* __restrict__ cbits){
  const int b = blockIdx.x, tid = threadIdx.x;
  if(b < 4096){
    float4 v = *(const float4*)(x + (size_t)b * 1024 + tid * 4);
    float m = fmaxf(fmaxf(v.x, v.y), fmaxf(v.z, v.w));
    m = blockMax256(m);
    if(tid == 0) rmax[b] = m;
  } else {
    int blk = b - 4096;
    int bb = blk >> 5, rg = blk & 31;
    const float* base = x + (size_t)bb * 1048576 + (size_t)rg * 32 * 1024;
    int col = tid * 4;
    float4 m = make_float4(-1e30f, -1e30f, -1e30f, -1e30f);
    for(int r = 0; r < 32; ++r){
      float4 v = *(const float4*)(base + r * 1024 + col);
      m.x = fmaxf(m.x, v.x); m.y = fmaxf(m.y, v.y);
      m.z = fmaxf(m.z, v.z); m.w = fmaxf(m.w, v.w);
    }
    unsigned* cb = cbits + (bb << 10) + col;
    atomicMax(cb + 0, fkey(m.x)); atomicMax(cb + 1, fkey(m.y));
    atomicMax(cb + 2, fkey(m.z)); atomicMax(cb + 3, fkey(m.w));
  }
}

// ---------- fused row max + col max over (ya + yb2) elementwise sum ----------
__global__ __launch_bounds__(256) void rcsum_k(const float* __restrict__ ya,
    const float* __restrict__ yb2, float* __restrict__ rmax, unsigned* __restrict__ cbits){
  const int b = blockIdx.x, tid = threadIdx.x;
  if(b < 4096){
    float4 v = *(const float4*)(ya + (size_t)b * 1024 + tid * 4);
    float4 u = *(const float4*)(yb2 + (size_t)b * 1024 + tid * 4);
    v.x += u.x; v.y += u.y; v.z += u.z; v.w += u.w;
    float m = fmaxf(fmaxf(v.x, v.y), fmaxf(v.z, v.w));
    m = blockMax256(m);
    if(tid == 0) rmax[b] = m;
  } else {
    int blk = b - 4096;
    int bb = blk >> 5, rg = blk & 31;
    const float* basea = ya  + (size_t)bb * 1048576 + (size_t)rg * 32 * 1024;
    const float* baseb = yb2 + (size_t)bb * 1048576 + (size_t)rg * 32 * 1024;
    int col = tid * 4;
    float4 m = make_float4(-1e30f, -1e30f, -1e30f, -1e30f);
    for(int r = 0; r < 32; ++r){
      float4 v = *(const float4*)(basea + r * 1024 + col);
      float4 u = *(const float4*)(baseb + r * 1024 + col);
      v.x += u.x; v.y += u.y; v.z += u.z; v.w += u.w;
      m.x = fmaxf(m.x, v.x); m.y = fmaxf(m.y, v.y);
      m.z = fmaxf(m.z, v.z); m.w = fmaxf(m.w, v.w);
    }
    unsigned* cb = cbits + (bb << 10) + col;
    atomicMax(cb + 0, fkey(m.x)); atomicMax(cb + 1, fkey(m.y));
    atomicMax(cb + 2, fkey(m.z)); atomicMax(cb + 3, fkey(m.w));
  }
}

// ---------- mutual matching elementwise ----------
__global__ __launch_bounds__(256) void mmapply_k(const float* __restrict__ x,
    const float* __restrict__ rmax, const unsigned* __restrict__ cbits,
    float* __restrict__ out){
  int idx4 = blockIdx.x * 256 + threadIdx.x;
  int b = idx4 >> 18;
  int rem = idx4 & 262143;
  int q = rem >> 8;
  int k = (rem & 255) * 4;
  float4 v = ((const float4*)x)[idx4];
  float ra = rmax[(b << 10) + q] + EPSF;
  const unsigned* cb = cbits + (b << 10) + k;
  float4 o;
  o.x = v.x * v.x * v.x / (ra * (fdec(cb[0]) + EPSF));
  o.y = v.y * v.y * v.y / (ra * (fdec(cb[1]) + EPSF));
  o.z = v.z * v.z * v.z / (ra * (fdec(cb[2]) + EPSF));
  o.w = v.w * v.w * v.w / (ra * (fdec(cb[3]) + EPSF));
  ((float4*)out)[idx4] = o;
}

// ---------- MFMA implicit-GEMM L1 (r17-proven: gather + prefetch + swizzle + byte addrs) ----------
__global__ __launch_bounds__(256)
void convmm_k(const unsigned short* __restrict__ gin, unsigned short* __restrict__ gout,
              const unsigned short* __restrict__ wpack, const float* __restrict__ bias,
              unsigned inElem, unsigned outElem, unsigned zeroElem){
  __shared__ unsigned short sh[13600];          // [ci][34 rows][40 cols]
  const int tid = threadIdx.x;
  const int blk = ((blockIdx.x & 7) << 8) | (blockIdx.x >> 3);   // 2048 = 8 x 256
  const int path = blk >> 10;
  const int hw = blk & 1023;
  const int h = hw >> 5, w = hw & 31;
  const unsigned inB = inElem + (unsigned)path * 10485760u;
  const unsigned outB = outElem + (unsigned)path * 10485760u;

  for(int i = tid; i < 6800; i += 256) ((unsigned*)sh)[i] = 0u;
  __syncthreads();
  for(int idx = tid; idx < 2560; idx += 256){
    int ci = idx >> 8, s = (idx & 255) * 4;
    ushort4 v = *(const ushort4*)(gin + inB + ci * 1048576 + hw * 1024 + s);
    *(ushort4*)(sh + ci * 1360 + (1 + (s >> 5)) * 40 + 4 + (s & 31)) = v;
  }
  __syncthreads();

  const int l = tid & 63, wv = tid >> 6;
  const int g = l >> 4, n = l & 15;

  bf16x8 af[6];
  #pragma unroll
  for(int sl = 0; sl < 6; ++sl)
    af[sl] = *(const bf16x8*)(wpack + ((size_t)path * 16 + n) * 192 + sl * 32 + g * 8);
  f32x4 cb = *(const f32x4*)(bias + path * 16 + g * 4);

  unsigned b1i[24]; unsigned b2b[32]; unsigned msk2[4], msk5[4];
  const unsigned s0 = (unsigned)wv * 256u;
  #pragma unroll
  for(int gg = 0; gg < 4; ++gg){
    if(g == gg){
      #pragma unroll
      for(int sl = 0; sl < 3; ++sl){
        #pragma unroll
        for(int j = 0; j < 8; ++j){
          const int k = sl * 32 + gg * 8 + j;
          unsigned v = zeroElem;
          if(k < 90){
            const int ci = k / 9, t = k % 9;
            const int hh = h + t / 3 - 1, ww = w + t % 3 - 1;
            if((unsigned)hh < 32u && (unsigned)ww < 32u)
              v = inB + (unsigned)ci * 1048576u + (unsigned)((hh * 32 + ww) * 1024) + (unsigned)n;
          }
          b1i[sl * 8 + j] = (v + s0) * 2u;       // BYTE offset
        }
      }
      #pragma unroll
      for(int sl = 2; sl < 6; ++sl){
        #pragma unroll
        for(int j = 0; j < 8; ++j){
          const int k = sl * 32 + gg * 8 + j;
          const int kp = (k >= 90 && k < 180) ? (k - 90) : 0;
          const int ci = kp / 9, t = kp % 9;
          b2b[(sl - 2) * 8 + j] = (unsigned)(ci * 1360 + (t / 3) * 40 + 3 + (t % 3) + n);
        }
      }
      #pragma unroll
      for(int p = 0; p < 4; ++p){
        const int ka = 64 + gg * 8 + 2 * p, kb = ka + 1;
        msk2[p] = ((ka >= 90) ? 0xFFFFu : 0u) | ((kb >= 90) ? 0xFFFF0000u : 0u);
        const int kc = 160 + gg * 8 + 2 * p, kd = kc + 1;
        msk5[p] = ((kc < 180) ? 0xFFFFu : 0u) | ((kd < 180) ? 0xFFFF0000u : 0u);
      }
    }
  }

  unsigned sb[4]; bool sv[4];
  #pragma unroll
  for(int r = 0; r < 4; ++r){
    const int co = g * 4 + r;
    sv[r] = (co < 10);
    sb[r] = (outB + (unsigned)co * 1048576u + (unsigned)(hw * 1024) + s0 + (unsigned)n) * 2u;
  }
  unsigned rowcs = (s0 >> 5) * 40u;

  const char* ginc = (const char*)gin;
  char* goutc = (char*)gout;

  unsigned short ga[24], gb[24];
  #pragma unroll
  for(int m = 0; m < 24; ++m) ga[m] = *(const unsigned short*)(ginc + b1i[m]);
  #pragma unroll
  for(int m = 0; m < 24; ++m) b1i[m] += 32u;

#define CMM_STEP(CUR, NXT, RDELTA)                                                \
  {                                                                               \
    _Pragma("unroll")                                                             \
    for(int m = 0; m < 24; ++m) NXT[m] = *(const unsigned short*)(ginc + b1i[m]); \
    _Pragma("unroll")                                                             \
    for(int m = 0; m < 24; ++m) b1i[m] += 32u;                                    \
    union { unsigned u[4]; bf16x8 v; } B0, B1, B2, B3, B4, B5;                    \
    _Pragma("unroll")                                                             \
    for(int p = 0; p < 4; ++p){                                                   \
      B0.u[p] = (unsigned)CUR[2*p]    | ((unsigned)CUR[2*p+1] << 16);             \
      B1.u[p] = (unsigned)CUR[8+2*p]  | ((unsigned)CUR[8+2*p+1] << 16);           \
      unsigned glo = (unsigned)CUR[16+2*p] | ((unsigned)CUR[16+2*p+1] << 16);     \
      unsigned llo = (unsigned)sh[b2b[2*p] + rowcs] |                             \
                     ((unsigned)sh[b2b[2*p+1] + rowcs] << 16);                    \
      B2.u[p] = glo | (llo & msk2[p]);                                            \
      B3.u[p] = (unsigned)sh[b2b[8+2*p]  + rowcs] |                               \
                ((unsigned)sh[b2b[8+2*p+1]  + rowcs] << 16);                      \
      B4.u[p] = (unsigned)sh[b2b[16+2*p] + rowcs] |                               \
                ((unsigned)sh[b2b[16+2*p+1] + rowcs] << 16);                      \
      B5.u[p] = ((unsigned)sh[b2b[24+2*p] + rowcs] |                              \
                 ((unsigned)sh[b2b[24+2*p+1] + rowcs] << 16)) & msk5[p];          \
    }                                                                             \
    rowcs += (RDELTA);                                                            \
    __builtin_amdgcn_s_setprio(1);                                                \
    f32x4 acc = __builtin_amdgcn_mfma_f32_16x16x32_bf16(af[0], B0.v, cb, 0, 0, 0);\
    acc = __builtin_amdgcn_mfma_f32_16x16x32_bf16(af[1], B1.v, acc, 0, 0, 0);     \
    acc = __builtin_amdgcn_mfma_f32_16x16x32_bf16(af[2], B2.v, acc, 0, 0, 0);     \
    acc = __builtin_amdgcn_mfma_f32_16x16x32_bf16(af[3], B3.v, acc, 0, 0, 0);     \
    acc = __builtin_amdgcn_mfma_f32_16x16x32_bf16(af[4], B4.v, acc, 0, 0, 0);     \
    acc = __builtin_amdgcn_mfma_f32_16x16x32_bf16(af[5], B5.v, acc, 0, 0, 0);     \
    __builtin_amdgcn_s_setprio(0);                                                \
    _Pragma("unroll")                                                             \
    for(int r = 0; r < 4; ++r){                                                   \
      if(sv[r])                                                                   \
        *(unsigned short*)(goutc + sb[r]) = f2bf(fmaxf(acc[r], 0.f));             \
    }                                                                             \
    _Pragma("unroll")                                                             \
    for(int r = 0; r < 4; ++r) sb[r] += 32u;                                      \
  }

  for(int itp = 0; itp < 8; ++itp){
    CMM_STEP(ga, gb, 16u)
    CMM_STEP(gb, ga, 24u)
  }
#undef CMM_STEP
}

// ---------- fused dual-path conv layer L0 (VALU, r5-proven) + XCD swizzle ----------
template<int CI, typename TI, typename TO>
__global__ __launch_bounds__(128, 4) void conv12_k(
    const TI* __restrict__ in, TO* __restrict__ out,
    const float* __restrict__ wq, const float* __restrict__ wsp,
    const float* __restrict__ bq, const float* __restrict__ bsp,
    size_t in_pstride){
  __shared__ float P[18][36];
  const int tid = threadIdx.x;
  const int blk = ((blockIdx.x & 7) << 9) | (blockIdx.x >> 3);   // 4096 = 8 x 512
  const int path = blk >> 11;
  const int r0 = blk & 2047;
  const int strip = r0 & 1;
  const int hw = r0 >> 1;
  const int w = hw & 31, h = hw >> 5;
  const int lr = tid >> 3;
  const int c  = (tid & 7) * 4;
  const int own = hw * 1024 + strip * 512 + tid * 4;
  const int halo_src = hw * 1024 + (strip ? 15 * 32 : 16 * 32) + (tid & 7) * 4;
  const int hrow = strip ? 0 : 17;
  const float* wA = path ? wsp : wq;
  const float* wB = path ? wq : wsp;
  const TI* inp = in + (size_t)path * in_pstride;
  TO* outp = out + (size_t)path * 10485760;

  bool valid[9];
  #pragma unroll
  for(int dh = 0; dh < 3; ++dh)
    #pragma unroll
    for(int dw = 0; dw < 3; ++dw)
      valid[dh * 3 + dw] = ((unsigned)(h + dh - 1) < 32u) && ((unsigned)(w + dw - 1) < 32u);

  for(int i = tid; i < 18 * 36; i += 128) ((float*)P)[i] = 0.f;

  float acc[10][4];
  #pragma unroll
  for(int co = 0; co < 10; ++co){
    float bv = bq[co] + bsp[co];
    acc[co][0] = bv; acc[co][1] = bv; acc[co][2] = bv; acc[co][3] = bv;
  }

  for(int ci = 0; ci < CI; ++ci){
    const TI* base = inp + (size_t)ci * 1048576;
    float4 qv[9];
    #pragma unroll
    for(int dh = 0; dh < 3; ++dh){
      #pragma unroll
      for(int dw = 0; dw < 3; ++dw){
        const int t = dh * 3 + dw;
        float4 vv = make_float4(0.f, 0.f, 0.f, 0.f);
        if(valid[t]) vv = ld4(base + own + ((dh - 1) * 32 + (dw - 1)) * 1024);
        qv[t] = vv;
      }
    }
    float4 hv = make_float4(0.f, 0.f, 0.f, 0.f);
    if(tid < 8) hv = ld4(base + halo_src);

    __syncthreads();
    *(float4*)&P[1 + lr][c] = qv[4];
    if(tid < 8) *(float4*)&P[hrow][tid * 4] = hv;
    __syncthreads();

    float pr[3][6];
    #pragma unroll
    for(int k1 = 0; k1 < 3; ++k1){
      const float* row = &P[lr + k1][0];
      float4 mid = *(const float4*)(row + c);
      pr[k1][0] = row[c == 0 ? 32 : c - 1];
      pr[k1][1] = mid.x; pr[k1][2] = mid.y; pr[k1][3] = mid.z; pr[k1][4] = mid.w;
      pr[k1][5] = row[c + 4];
    }

    #pragma unroll
    for(int co = 0; co < 10; ++co){
      const float* wa = wA + (co * CI + ci) * 9;
      const float* wb = wB + (co * CI + ci) * 9;
      #pragma unroll
      for(int t = 0; t < 9; ++t){
        float wv = wa[t];
        acc[co][0] += wv * qv[t].x; acc[co][1] += wv * qv[t].y;
        acc[co][2] += wv * qv[t].z; acc[co][3] += wv * qv[t].w;
      }
      #pragma unroll
      for(int k1 = 0; k1 < 3; ++k1){
        #pragma unroll
        for(int k2 = 0; k2 < 3; ++k2){
          float wv = wb[k1 * 3 + k2];
          #pragma unroll
          for(int j = 0; j < 4; ++j) acc[co][j] += wv * pr[k1][k2 + j];
        }
      }
    }
  }

  #pragma unroll
  for(int co = 0; co < 10; ++co){
    float4 r;
    r.x = fmaxf(acc[co][0], 0.f); r.y = fmaxf(acc[co][1], 0.f);
    r.z = fmaxf(acc[co][2], 0.f); r.w = fmaxf(acc[co][3], 0.f);
    st4(outp + (size_t)co * 1048576 + own, r);
  }
}

// ---------- path-split last layer (CO=1): plain stores, path0->y0b, path1->y1b ----------
__global__ __launch_bounds__(128, 4) void conv3_k(
    const __hip_bfloat16* __restrict__ in,      // t2 base: [path][10][1M]
    const float* __restrict__ wq, const float* __restrict__ wsp,
    const float* __restrict__ bq, const float* __restrict__ bsp,
    float* __restrict__ y0b, float* __restrict__ y1b){
  __shared__ float P[18][36];
  const int tid = threadIdx.x;
  const int blk = ((blockIdx.x & 7) << 9) | (blockIdx.x >> 3);   // 4096 = 8 x 512
  const int path = blk >> 11;
  const int r0 = blk & 2047;
  const int strip = r0 & 1;
  const int hw = r0 >> 1;
  const int w = hw & 31, h = hw >> 5;
  const int lr = tid >> 3;
  const int c  = (tid & 7) * 4;
  const int own = hw * 1024 + strip * 512 + tid * 4;
  const int halo_src = hw * 1024 + (strip ? 15 * 32 : 16 * 32) + (tid & 7) * 4;
  const int hrow = strip ? 0 : 17;
  const float* wA = path ? wsp : wq;
  const float* wB = path ? wq : wsp;
  const __hip_bfloat16* inp = in + (size_t)path * 10485760;
  float* yout = path ? y1b : y0b;

  bool valid[9];
  #pragma unroll
  for(int dh = 0; dh < 3; ++dh)
    #pragma unroll
    for(int dw = 0; dw < 3; ++dw)
      valid[dh * 3 + dw] = ((unsigned)(h + dh - 1) < 32u) && ((unsigned)(w + dw - 1) < 32u);

  for(int i = tid; i < 18 * 36; i += 128) ((float*)P)[i] = 0.f;

  float bv = bq[0] + bsp[0];
  float a0 = bv, a1 = bv, a2 = bv, a3 = bv;

  for(int ci = 0; ci < 10; ++ci){
    const __hip_bfloat16* base = inp + (size_t)ci * 1048576;
    float4 qv[9];
    #pragma unroll
    for(int dh = 0; dh < 3; ++dh){
      #pragma unroll
      for(int dw = 0; dw < 3; ++dw){
        const int t = dh * 3 + dw;
        float4 vv = make_float4(0.f, 0.f, 0.f, 0.f);
        if(valid[t]) vv = ld4(base + own + ((dh - 1) * 32 + (dw - 1)) * 1024);
        qv[t] = vv;
      }
    }
    float4 hv = make_float4(0.f, 0.f, 0.f, 0.f);
    if(tid < 8) hv = ld4(base + halo_src);

    __syncthreads();
    *(float4*)&P[1 + lr][c] = qv[4];
    if(tid < 8) *(float4*)&P[hrow][tid * 4] = hv;
    __syncthreads();

    float pr[3][6];
    #pragma unroll
    for(int k1 = 0; k1 < 3; ++k1){
      const float* row = &P[lr + k1][0];
      float4 mid = *(const float4*)(row + c);
      pr[k1][0] = row[c == 0 ? 32 : c - 1];
      pr[k1][1] = mid.x; pr[k1][2] = mid.y; pr[k1][3] = mid.z; pr[k1][4] = mid.w;
      pr[k1][5] = row[c + 4];
    }

    const float* wa = wA + ci * 9;
    const float* wb = wB + ci * 9;
    #pragma unroll
    for(int t = 0; t < 9; ++t){
      float wv = wa[t];
      a0 += wv * qv[t].x; a1 += wv * qv[t].y;
      a2 += wv * qv[t].z; a3 += wv * qv[t].w;
    }
    #pragma unroll
    for(int k1 = 0; k1 < 3; ++k1){
      #pragma unroll
      for(int k2 = 0; k2 < 3; ++k2){
        float wv = wb[k1 * 3 + k2];
        a0 += wv * pr[k1][k2 + 0];
        a1 += wv * pr[k1][k2 + 1];
        a2 += wv * pr[k1][k2 + 2];
        a3 += wv * pr[k1][k2 + 3];
      }
    }
  }

  float4 r;
  r.x = fmaxf(a0, 0.f); r.y = fmaxf(a1, 0.f);
  r.z = fmaxf(a2, 0.f); r.w = fmaxf(a3, 0.f);
  *(float4*)(yout + own) = r;
}

// ---------- mm2 + mask + softmax fused over (y + y2), one block per (b,q) row ----------
// attn may alias y2 (in-place): each thread reads its float4 before writing it.
__global__ __launch_bounds__(256) void softmax_k(
    const float* __restrict__ y, const float* __restrict__ y2,
    const float* __restrict__ rmax,
    const unsigned* __restrict__ cbits, const void* __restrict__ mask,
    const int* __restrict__ mode, float* __restrict__ attn){
  int row = blockIdx.x;          // b*1024+q
  int b = row >> 10;
  int tid = threadIdx.x;
  int kc = tid * 4;
  float ra = rmax[row] + EPSF;
  float4 v = *(const float4*)(y  + (size_t)row * 1024 + kc);
  float4 u = *(const float4*)(y2 + (size_t)row * 1024 + kc);
  v.x += u.x; v.y += u.y; v.z += u.z; v.w += u.w;
  int md = *mode;
  float vv[4] = {v.x, v.y, v.z, v.w};
  float s[4];
  #pragma unroll
  for(int j = 0; j < 4; ++j){
    int k = kc + j;
    float cb = fdec(cbits[(b << 10) + k]) + EPSF;
    float m = vv[j] * vv[j] * vv[j] / (ra * cb);
    bool msk;
    if(md == 0)      msk = ((const int*)mask)[(b << 10) + k] != 0;
    else if(md == 1) msk = ((const float*)mask)[(b << 10) + k] != 0.f;
    else             msk = ((const unsigned char*)mask)[(b << 10) + k] != 0;
    if(msk) m = 1e-4f;
    s[j] = m * TEMPF;
  }
  float mx = fmaxf(fmaxf(s[0], s[1]), fmaxf(s[2], s[3]));
  mx = blockMax256(mx);
  float e[4]; float sum = 0.f;
  #pragma unroll
  for(int j = 0; j < 4; ++j){ e[j] = expf(s[j] - mx); sum += e[j]; }
  sum = blockSum256(sum);
  float inv = 1.0f / sum;
  float4 o; o.x = e[0] * inv; o.y = e[1] * inv; o.z = e[2] * inv; o.w = e[3] * inv;
  *(float4*)(attn + (size_t)row * 1024 + kc) = o;
}

// ---------- partial[ks][b,c,q] = sum_{k in split ks} v[b,c,k]*attn[b,q,k] ----------
__global__ __launch_bounds__(256) void bmm_k(const float* __restrict__ v,
    const float* __restrict__ attn, float* __restrict__ part){
  __shared__ float At[64][68];
  __shared__ float Bt[64][68];
  int b  = blockIdx.y >> 2;
  int ks = blockIdx.y & 3;
  int ct = blockIdx.x >> 4, qt = blockIdx.x & 15;
  int tid = threadIdx.x;
  int c0 = ct * 64, q0 = qt * 64;
  int tx = tid & 15, ty = tid >> 4;
  float acc[4][4] = {};
  for(int k0 = ks * 256; k0 < ks * 256 + 256; k0 += 64){
    #pragma unroll
    for(int l = 0; l < 4; ++l){
      int r = (tid >> 4) + l * 16;
      int cc = (tid & 15) * 4;
      *(float4*)&At[r][cc] = *(const float4*)(v    + ((size_t)b * 256  + c0 + r) * 1024 + k0 + cc);
      *(float4*)&Bt[r][cc] = *(const float4*)(attn + ((size_t)b * 1024 + q0 + r) * 1024 + k0 + cc);
    }
    __syncthreads();
    #pragma unroll 4
    for(int kk = 0; kk < 64; ++kk){
      float a_[4], b_[4];
      #pragma unroll
      for(int i = 0; i < 4; ++i){ a_[i] = At[ty * 4 + i][kk]; b_[i] = Bt[tx * 4 + i][kk]; }
      #pragma unroll
      for(int i = 0; i < 4; ++i)
        #pragma unroll
        for(int j = 0; j < 4; ++j) acc[i][j] += a_[i] * b_[j];
    }
    __syncthreads();
  }
  float* pb = part + (size_t)ks * 1048576;
  #pragma unroll
  for(int i = 0; i < 4; ++i){
    float4 r; r.x = acc[i][0]; r.y = acc[i][1]; r.z = acc[i][2]; r.w = acc[i][3];
    *(float4*)(pb + ((size_t)b * 256 + c0 + ty * 4 + i) * 1024 + q0 + tx * 4) = r;
  }
}

__global__ __launch_bounds__(256) void bmmred_k(const float* __restrict__ part,
                                                float* __restrict__ out){
  int i = blockIdx.x * 256 + threadIdx.x;      // over 262144 float4
  const float4* p = (const float4*)part;
  float4 a = p[i], b = p[i + 262144], cc = p[i + 524288], d = p[i + 786432];
  float4 o;
  o.x = a.x + b.x + cc.x + d.x;
  o.y = a.y + b.y + cc.y + d.y;
  o.z = a.z + b.z + cc.z + d.z;
  o.w = a.w + b.w + cc.w + d.w;
  ((float4*)out)[i] = o;
}

extern "C" void kernel_launch(void* const* d_in, const int* in_sizes, int n_in,
                              void* d_out, int out_size, void* d_ws, size_t ws_size,
                              hipStream_t stream){
  (void)in_sizes; (void)n_in; (void)out_size; (void)ws_size;
  const float* corr = (const float*)d_in[0];
  const float* v    = (const float*)d_in[1];
  const void*  mask = d_in[2];
  const float* wq[3]  = {(const float*)d_in[3],  (const float*)d_in[7],  (const float*)d_in[11]};
  const float* bq[3]  = {(const float*)d_in[4],  (const float*)d_in[8],  (const float*)d_in[12]};
  const float* wsp[3] = {(const float*)d_in[5],  (const float*)d_in[9],  (const float*)d_in[13]};
  const float* bsp[3] = {(const float*)d_in[6],  (const float*)d_in[10], (const float*)d_in[14]};
  float* out = (float*)d_out;

  // ---- workspace layout: total exactly 117,571,584 B (proven fit) ----
  char* ws = (char*)d_ws;
  float* x0 = (float*)(ws);                      // 16.78 MB f32 (mm1 out; then conv3 path1 out; then attn)
  float* y  = (float*)(ws + 16777216);           // 16.78 MB f32 (conv3 path0 out)
  char* aux = ws + 33554432;                     // 128 KiB
  float*    rmax1 = (float*)(aux);
  unsigned* cb1   = (unsigned*)(aux + 16384);
  float*    rmax2 = (float*)(aux + 32768);
  unsigned* cb2   = (unsigned*)(aux + 49152);
  int*      flag  = (int*)(aux + 65536);
  unsigned short* wp = (unsigned short*)(aux + 69632);  // 12,288 B
  float*          bs = (float*)(aux + 81920);          // 128 B
  unsigned* zeros = (unsigned*)(aux + 98304);          // 4,096 B zero stripe
  char* treg = ws + 33685504;                    // 2 x 41,943,040 B bf16 dual-path buffers
  __hip_bfloat16* t1 = (__hip_bfloat16*)(treg);                 // [path][10][1M]
  __hip_bfloat16* t2 = (__hip_bfloat16*)(treg + 41943040);
  float* attn = x0;                              // softmax writes in-place over x0 (y2 path1)
  float* part = (float*)treg;

  // u16-element offsets within ws (for convmm 32-bit addressing)
  const unsigned t1Elem   = 33685504u / 2u;
  const unsigned t2Elem   = 75628544u / 2u;
  const unsigned zeroElem = 33652736u / 2u;

  setup_k<<<41, 256, 0, stream>>>((const unsigned*)mask, flag, cb1, cb2, zeros,
                                  wq[1], wsp[1], bq[1], bsp[1], wp, bs);
  rcmax_k<<<4224, 256, 0, stream>>>(corr, rmax1, cb1);
  mmapply_k<<<4096, 256, 0, stream>>>(corr, rmax1, cb1, x0);

  for(int bb = 0; bb < 4; ++bb){
    const float* xb = x0 + (size_t)bb * 1048576;
    float*       yb  = y  + (size_t)bb * 1048576;
    float*       y2b = x0 + (size_t)bb * 1048576;   // x0[bb] dead after L0(bb)
    conv12_k<1, float, __hip_bfloat16><<<4096, 128, 0, stream>>>(
        xb, t1, wq[0], wsp[0], bq[0], bsp[0], 0);
    convmm_k<<<2048, 256, 0, stream>>>(
        (const unsigned short*)ws, (unsigned short*)ws, wp, bs, t1Elem, t2Elem, zeroElem);
    conv3_k<<<4096, 128, 0, stream>>>(
        t2, wq[2], wsp[2], bq[2], bsp[2], yb, y2b);
  }

  rcsum_k<<<4224, 256, 0, stream>>>(y, x0, rmax2, cb2);
  softmax_k<<<4096, 256, 0, stream>>>(y, x0, rmax2, cb2, mask, flag, attn);
  bmm_k<<<dim3(64, 16), 256, 0, stream>>>(v, attn, part);
  bmmred_k<<<1024, 256, 0, stream>>>(part, out);
}